// Round 3
// baseline (9760.749 us; speedup 1.0000x reference)
//
#include <hip/hip_runtime.h>

typedef unsigned int uint;
typedef unsigned short ushort;

// ---------- helpers ----------
__device__ __forceinline__ float bf2f(ushort u){ return __uint_as_float(((uint)u) << 16); }
__device__ __forceinline__ ushort f2bf(float f){            // RTNE
  uint u = __float_as_uint(f);
  u += 0x7fffu + ((u >> 16) & 1u);
  return (ushort)(u >> 16);
}
// monotone float<->uint map for atomicMax on signed floats
__device__ __forceinline__ uint encf(float x){
  uint u = __float_as_uint(x);
  return u ^ ((uint)((int)u >> 31) | 0x80000000u);
}
__device__ __forceinline__ float decf(uint k){
  uint u = (k & 0x80000000u) ? (k ^ 0x80000000u) : ~k;
  return __uint_as_float(u);
}
__device__ __forceinline__ bool is_f32(const uint* __restrict__ flag){ return flag[1] > 4096u; }

// ---------- edge dtype detect: OR all odd 32-bit words in first nwords words ----------
// int64 non-negative values -> odd (high) words all zero. int32 -> odd words are values.
__global__ void k_detect_edge(const uint* __restrict__ w, int nwords, uint* __restrict__ flag){
  uint v = 0;
  for (int i = blockIdx.x * blockDim.x + threadIdx.x; 2 * i + 1 < nwords;
       i += gridDim.x * blockDim.x)
    v |= w[2 * i + 1];
  #pragma unroll
  for (int o = 32; o > 0; o >>= 1) v |= __shfl_xor(v, o);
  if ((threadIdx.x & 63) == 0 && v) atomicOr(&flag[0], 1u);
}

// ---------- float dtype detect on x: count words whose LOW ushort has exponent>=0xC0 ----------
// f32 data: low ushort = uniform mantissa bits -> ~25% hits. bf16 pairs of N(0,1): ~0 hits.
__global__ void k_detect_f32(const uint* __restrict__ w, int nwords, uint* __restrict__ flag){
  uint c = 0;
  for (int i = blockIdx.x * blockDim.x + threadIdx.x; i < nwords;
       i += gridDim.x * blockDim.x){
    uint eb = (w[i] >> 7) & 0xFFu;
    c += (eb >= 0xC0u) ? 1u : 0u;
  }
  #pragma unroll
  for (int o = 32; o > 0; o >>= 1) c += __shfl_xor(c, o);
  if ((threadIdx.x & 63) == 0 && c) atomicAdd(&flag[1], c);
}

// ---------- convert edge_index (+self loops) to int32 src/dst ----------
__global__ void k_convert(const void* __restrict__ ei, int E, int Ep,
                          const uint* __restrict__ flag,
                          int* __restrict__ src, int* __restrict__ dst){
  int e = blockIdx.x * blockDim.x + threadIdx.x;
  if (e >= Ep) return;
  if (e >= E){ src[e] = e - E; dst[e] = e - E; return; }
  if (flag[0]){                                 // int32 layout
    const int* p = (const int*)ei;
    src[e] = p[e]; dst[e] = p[(size_t)E + e];
  } else {                                      // int64 layout
    const long long* p = (const long long*)ei;
    src[e] = (int)p[e]; dst[e] = (int)p[(size_t)E + e];
  }
}

// ---------- normalize a float tensor (f32 or packed bf16, per flag) -> f32 ----------
__global__ void k_cvt(const void* __restrict__ in, float* __restrict__ out, int n8,
                      const uint* __restrict__ flag){
  int t = blockIdx.x * blockDim.x + threadIdx.x;
  if (t >= n8) return;
  int i = t * 8;
  float f[8];
  if (is_f32(flag)){
    const float4* p = (const float4*)((const float*)in + i);
    float4 a = p[0], b = p[1];
    f[0]=a.x; f[1]=a.y; f[2]=a.z; f[3]=a.w; f[4]=b.x; f[5]=b.y; f[6]=b.z; f[7]=b.w;
  } else {
    uint4 v = *(const uint4*)((const ushort*)in + i);
    const uint* vw = (const uint*)&v;
    #pragma unroll
    for (int p = 0; p < 4; p++){
      f[2*p]   = __uint_as_float(vw[p] << 16);
      f[2*p+1] = __uint_as_float(vw[p] & 0xffff0000u);
    }
  }
  *(float4*)(out + i)     = make_float4(f[0], f[1], f[2], f[3]);
  *(float4*)(out + i + 4) = make_float4(f[4], f[5], f[6], f[7]);
}

// ---------- GEMM: O[N,M] = X[N,128] @ W[128,M], all f32 ----------
template<int M, int RT>
__global__ __launch_bounds__(256) void k_gemm(const float* __restrict__ X,
    const float* __restrict__ W, float* __restrict__ O, int N){
  constexpr int K = 128;
  __shared__ float Wl[K * M];
  for (int i = threadIdx.x; i < K * M; i += 256) Wl[i] = W[i];
  __syncthreads();
  constexpr int CG = M / 8;                 // column groups of 8
  int cx = threadIdx.x % CG;
  int ry = threadIdx.x / CG;
  int row0 = blockIdx.x * 64 + ry * RT;     // 64 rows per block
  float acc[RT][8];
  #pragma unroll
  for (int r = 0; r < RT; r++)
    #pragma unroll
    for (int c = 0; c < 8; c++) acc[r][c] = 0.f;

  for (int kb = 0; kb < K; kb += 4){
    float4 xv[RT];
    #pragma unroll
    for (int r = 0; r < RT; r++){
      int row = row0 + r; if (row >= N) row = N - 1;
      xv[r] = *(const float4*)(X + (size_t)row * K + kb);
    }
    #pragma unroll
    for (int kk = 0; kk < 4; kk++){
      float wr[8];
      #pragma unroll
      for (int c = 0; c < 8; c++) wr[c] = Wl[(kb + kk) * M + cx * 8 + c];
      #pragma unroll
      for (int r = 0; r < RT; r++){
        float xf = ((const float*)&xv[r])[kk];
        #pragma unroll
        for (int c = 0; c < 8; c++) acc[r][c] = fmaf(xf, wr[c], acc[r][c]);
      }
    }
  }
  #pragma unroll
  for (int r = 0; r < RT; r++){
    int row = row0 + r;
    if (row < N){
      float* op = O + (size_t)row * M + cx * 8;
      *(float4*)(op)     = make_float4(acc[r][0], acc[r][1], acc[r][2], acc[r][3]);
      *(float4*)(op + 4) = make_float4(acc[r][4], acc[r][5], acc[r][6], acc[r][7]);
    }
  }
}

// ---------- per (node,head) attention dots ----------
template<int H>
__global__ void k_att(const float* __restrict__ Hf, const float* __restrict__ attS,
                      const float* __restrict__ attD,
                      float* __restrict__ aS, float* __restrict__ aD, int NH){
  int t = blockIdx.x * blockDim.x + threadIdx.x;
  if (t >= NH) return;
  int h = t % H;
  const float* hp = Hf + (size_t)t * 64;
  float s = 0.f, d = 0.f;
  #pragma unroll
  for (int cb = 0; cb < 64; cb += 4){
    float4 hv = *(const float4*)(hp + cb);
    float4 sv = *(const float4*)(attS + h * 64 + cb);
    float4 dv = *(const float4*)(attD + h * 64 + cb);
    s = fmaf(hv.x, sv.x, s); s = fmaf(hv.y, sv.y, s);
    s = fmaf(hv.z, sv.z, s); s = fmaf(hv.w, sv.w, s);
    d = fmaf(hv.x, dv.x, d); d = fmaf(hv.y, dv.y, d);
    d = fmaf(hv.z, dv.z, d); d = fmaf(hv.w, dv.w, d);
  }
  aS[t] = s; aD[t] = d;
}

// ---------- pass 1: logits + segment max ----------
template<int H>
__global__ void k_emax(const int* __restrict__ src, const int* __restrict__ dst,
                       const float* __restrict__ aS, const float* __restrict__ aD,
                       uint* __restrict__ mkey, int Ep){
  int e = blockIdx.x * blockDim.x + threadIdx.x;
  if (e >= Ep) return;
  int s = src[e], d = dst[e];
  #pragma unroll
  for (int h = 0; h < H; h++){
    float v = aS[s * H + h] + aD[d * H + h];
    v = v > 0.f ? v : 0.2f * v;                 // leaky_relu 0.2
    atomicMax(&mkey[d * H + h], encf(v));
  }
}

// ---------- pass 2: exp + segment sum (logit recomputed) ----------
template<int H>
__global__ void k_esum(const int* __restrict__ src, const int* __restrict__ dst,
                       const float* __restrict__ aS, const float* __restrict__ aD,
                       const uint* __restrict__ mkey, float* __restrict__ ssum, int Ep){
  int e = blockIdx.x * blockDim.x + threadIdx.x;
  if (e >= Ep) return;
  int s = src[e], d = dst[e];
  #pragma unroll
  for (int h = 0; h < H; h++){
    float v = aS[s * H + h] + aD[d * H + h];
    v = v > 0.f ? v : 0.2f * v;
    float m = decf(mkey[d * H + h]);
    atomicAdd(&ssum[d * H + h], __expf(v - m));
  }
}

// ---------- pass 3: alpha * h[src] scatter-add; thread = (edge, head, 8ch) ----------
template<int H>
__global__ void k_msg(const int* __restrict__ src, const int* __restrict__ dst,
                      const float* __restrict__ aS, const float* __restrict__ aD,
                      const uint* __restrict__ mkey, const float* __restrict__ ssum,
                      const float* __restrict__ Hf, float* __restrict__ acc, int Ep){
  int t = blockIdx.x * blockDim.x + threadIdx.x;
  constexpr int CH = H * 8;
  int e = t / CH;
  if (e >= Ep) return;
  int sub = t % CH;
  int h = sub >> 3;
  int c0 = (sub & 7) * 8;
  int s = src[e], d = dst[e];
  float v = aS[s * H + h] + aD[d * H + h];
  v = v > 0.f ? v : 0.2f * v;
  float alpha = __expf(v - decf(mkey[d * H + h])) / (ssum[d * H + h] + 1e-16f);
  const float* hp = Hf + ((size_t)s * H + h) * 64 + c0;
  float4 a = *(const float4*)(hp);
  float4 b = *(const float4*)(hp + 4);
  float* ap = acc + ((size_t)d * H + h) * 64 + c0;
  atomicAdd(ap + 0, alpha * a.x); atomicAdd(ap + 1, alpha * a.y);
  atomicAdd(ap + 2, alpha * a.z); atomicAdd(ap + 3, alpha * a.w);
  atomicAdd(ap + 4, alpha * b.x); atomicAdd(ap + 5, alpha * b.y);
  atomicAdd(ap + 6, alpha * b.z); atomicAdd(ap + 7, alpha * b.w);
}

// ---------- bias + ELU -> f32 (layer1 output / layer2 input) ----------
__global__ void k_elu(const float* __restrict__ acc, const float* __restrict__ bias,
                      float* __restrict__ O, int total){
  int t = (blockIdx.x * blockDim.x + threadIdx.x) * 8;
  if (t >= total) return;
  int col = t & 127;
  float4 a0 = *(const float4*)(acc + t);
  float4 a1 = *(const float4*)(acc + t + 4);
  float f[8] = {a0.x, a0.y, a0.z, a0.w, a1.x, a1.y, a1.z, a1.w};
  #pragma unroll
  for (int i = 0; i < 8; i++){
    float v = f[i] + bias[col + i];
    f[i] = v > 0.f ? v : expm1f(v);
  }
  *(float4*)(O + t)     = make_float4(f[0], f[1], f[2], f[3]);
  *(float4*)(O + t + 4) = make_float4(f[4], f[5], f[6], f[7]);
}

// ---------- bias -> output (bf16 or f32 per detected dtype) ----------
__global__ void k_out(const float* __restrict__ acc, const float* __restrict__ bias,
                      void* __restrict__ out, int total, const uint* __restrict__ flag){
  int t = (blockIdx.x * blockDim.x + threadIdx.x) * 8;
  if (t >= total) return;
  int col = t & 63;
  float4 a0 = *(const float4*)(acc + t);
  float4 a1 = *(const float4*)(acc + t + 4);
  float f[8] = {a0.x, a0.y, a0.z, a0.w, a1.x, a1.y, a1.z, a1.w};
  #pragma unroll
  for (int i = 0; i < 8; i++) f[i] += bias[col + i];
  if (is_f32(flag)){
    float* op = (float*)out + t;
    *(float4*)(op)     = make_float4(f[0], f[1], f[2], f[3]);
    *(float4*)(op + 4) = make_float4(f[4], f[5], f[6], f[7]);
  } else {
    uint4 o; uint* ow = (uint*)&o;
    #pragma unroll
    for (int p = 0; p < 4; p++)
      ow[p] = (uint)f2bf(f[2 * p]) | ((uint)f2bf(f[2 * p + 1]) << 16);
    *(uint4*)((ushort*)out + t) = o;
  }
}

extern "C" void kernel_launch(void* const* d_in, const int* in_sizes, int n_in,
                              void* d_out, int out_size, void* d_ws, size_t ws_size,
                              hipStream_t stream){
  const void* x   = d_in[0];
  const void* ei  = d_in[1];
  const void* W1  = d_in[2];
  const void* aS1w= d_in[3];
  const void* aD1w= d_in[4];
  const void* b1w = d_in[5];
  const void* W2  = d_in[6];
  const void* aS2w= d_in[7];
  const void* aD2w= d_in[8];
  const void* b2w = d_in[9];

  const int N  = in_sizes[0] / 128;
  const int E  = in_sizes[1] / 2;
  const int Ep = E + N;

  char* w = (char*)d_ws;
  size_t off = 0;
  auto alloc = [&](size_t bytes)->char*{
    char* p = w + off; off = (off + bytes + 255) & ~(size_t)255; return p;
  };
  uint*  flag  = (uint*) alloc(256);
  int*   src32 = (int*)  alloc((size_t)Ep * 4);
  int*   dst32 = (int*)  alloc((size_t)Ep * 4);
  float* Wf1   = (float*)alloc((size_t)128 * 128 * 4);
  float* aSf1  = (float*)alloc(128 * 4);
  float* aDf1  = (float*)alloc(128 * 4);
  float* bf1   = (float*)alloc(128 * 4);
  float* Wf2   = (float*)alloc((size_t)128 * 64 * 4);
  float* aSf2  = (float*)alloc(64 * 4);
  float* aDf2  = (float*)alloc(64 * 4);
  float* bf2   = (float*)alloc(64 * 4);
  float* aS1   = (float*)alloc((size_t)N * 2 * 4);
  float* aD1   = (float*)alloc((size_t)N * 2 * 4);
  uint*  m1    = (uint*) alloc((size_t)N * 2 * 4);
  float* s1    = (float*)alloc((size_t)N * 2 * 4);
  float* aS2   = (float*)alloc((size_t)N * 4);
  float* aD2   = (float*)alloc((size_t)N * 4);
  uint*  m2    = (uint*) alloc((size_t)N * 4);
  float* s2    = (float*)alloc((size_t)N * 4);
  float* A     = (float*)alloc((size_t)N * 128 * 4);  // xf, later h1 (post-ELU)
  float* B     = (float*)alloc((size_t)N * 128 * 4);  // hf (layer1), later g2 (layer2)
  float* acc   = (float*)alloc((size_t)N * 128 * 4);  // aggregation accumulator

  hipMemsetAsync(flag, 0, 8, stream);
  hipMemsetAsync(m1, 0, (size_t)N * 2 * 4, stream);   // encf makes 0 == -inf
  hipMemsetAsync(s1, 0, (size_t)N * 2 * 4, stream);
  hipMemsetAsync(m2, 0, (size_t)N * 4, stream);
  hipMemsetAsync(s2, 0, (size_t)N * 4, stream);
  hipMemsetAsync(acc, 0, (size_t)N * 128 * 4, stream);

  k_detect_edge<<<512, 256, 0, stream>>>((const uint*)ei, 2 * E, flag);
  k_detect_f32 <<<512, 256, 0, stream>>>((const uint*)x, 1 << 20, flag);

  int gbE = (Ep + 255) / 256;
  k_convert<<<gbE, 256, 0, stream>>>(ei, E, Ep, flag, src32, dst32);

  // normalize all float tensors to f32 workspace copies
  auto cvt = [&](const void* in, float* outp, int n){
    int n8 = n / 8;
    k_cvt<<<(n8 + 255) / 256, 256, 0, stream>>>(in, outp, n8, flag);
  };
  cvt(x,    A,    N * 128);
  cvt(W1,   Wf1,  128 * 128);
  cvt(aS1w, aSf1, 128);
  cvt(aD1w, aDf1, 128);
  cvt(b1w,  bf1,  128);
  cvt(W2,   Wf2,  128 * 64);
  cvt(aS2w, aSf2, 64);
  cvt(aD2w, aDf2, 64);
  cvt(b2w,  bf2,  64);

  int gemmb = (N + 63) / 64;
  // -------- layer 1 (H=2) --------
  k_gemm<128, 4><<<gemmb, 256, 0, stream>>>(A, Wf1, B, N);
  k_att<2><<<(N * 2 + 255) / 256, 256, 0, stream>>>(B, aSf1, aDf1, aS1, aD1, N * 2);
  k_emax<2><<<gbE, 256, 0, stream>>>(src32, dst32, aS1, aD1, m1, Ep);
  k_esum<2><<<gbE, 256, 0, stream>>>(src32, dst32, aS1, aD1, m1, s1, Ep);
  {
    int thr = Ep * 16;
    k_msg<2><<<(thr + 255) / 256, 256, 0, stream>>>(src32, dst32, aS1, aD1, m1, s1, B, acc, Ep);
  }
  k_elu<<<((N * 128 / 8) + 255) / 256, 256, 0, stream>>>(acc, bf1, A, N * 128);

  // -------- layer 2 (H=1) --------
  hipMemsetAsync(acc, 0, (size_t)N * 64 * 4, stream);
  k_gemm<64, 2><<<gemmb, 256, 0, stream>>>(A, Wf2, B, N);
  k_att<1><<<(N + 255) / 256, 256, 0, stream>>>(B, aSf2, aDf2, aS2, aD2, N);
  k_emax<1><<<gbE, 256, 0, stream>>>(src32, dst32, aS2, aD2, m2, Ep);
  k_esum<1><<<gbE, 256, 0, stream>>>(src32, dst32, aS2, aD2, m2, s2, Ep);
  {
    int thr = Ep * 8;
    k_msg<1><<<(thr + 255) / 256, 256, 0, stream>>>(src32, dst32, aS2, aD2, m2, s2, B, acc, Ep);
  }
  k_out<<<((N * 64 / 8) + 255) / 256, 256, 0, stream>>>(acc, bf2, d_out, N * 64, flag);
}

// Round 5
// 1058.010 us; speedup vs baseline: 9.2256x; 9.2256x over previous
//
#include <hip/hip_runtime.h>

typedef unsigned int uint;
typedef unsigned short ushort;

// ---------- helpers ----------
__device__ __forceinline__ ushort f2bf(float f){            // RTNE
  uint u = __float_as_uint(f);
  u += 0x7fffu + ((u >> 16) & 1u);
  return (ushort)(u >> 16);
}
__device__ __forceinline__ bool is_f32(const uint* __restrict__ flag){ return flag[1] > 4096u; }

// ---------- edge dtype detect ----------
__global__ void k_detect_edge(const uint* __restrict__ w, int nwords, uint* __restrict__ flag){
  uint v = 0;
  for (int i = blockIdx.x * blockDim.x + threadIdx.x; 2 * i + 1 < nwords;
       i += gridDim.x * blockDim.x)
    v |= w[2 * i + 1];
  #pragma unroll
  for (int o = 32; o > 0; o >>= 1) v |= __shfl_xor(v, o);
  if ((threadIdx.x & 63) == 0 && v) atomicOr(&flag[0], 1u);
}

// ---------- float dtype detect on x ----------
__global__ void k_detect_f32(const uint* __restrict__ w, int nwords, uint* __restrict__ flag){
  uint c = 0;
  for (int i = blockIdx.x * blockDim.x + threadIdx.x; i < nwords;
       i += gridDim.x * blockDim.x){
    uint eb = (w[i] >> 7) & 0xFFu;
    c += (eb >= 0xC0u) ? 1u : 0u;
  }
  #pragma unroll
  for (int o = 32; o > 0; o >>= 1) c += __shfl_xor(c, o);
  if ((threadIdx.x & 63) == 0 && c) atomicAdd(&flag[1], c);
}

// ---------- convert edge_index (+self loops) to int32 src/dst ----------
__global__ void k_convert(const void* __restrict__ ei, int E, int Ep,
                          const uint* __restrict__ flag,
                          int* __restrict__ src, int* __restrict__ dst){
  int e = blockIdx.x * blockDim.x + threadIdx.x;
  if (e >= Ep) return;
  if (e >= E){ src[e] = e - E; dst[e] = e - E; return; }
  if (flag[0]){
    const int* p = (const int*)ei;
    src[e] = p[e]; dst[e] = p[(size_t)E + e];
  } else {
    const long long* p = (const long long*)ei;
    src[e] = (int)p[e]; dst[e] = (int)p[(size_t)E + e];
  }
}

// ---------- normalize float tensor (f32 or packed bf16) -> f32 ----------
__global__ void k_cvt(const void* __restrict__ in, float* __restrict__ out, int n8,
                      const uint* __restrict__ flag){
  int t = blockIdx.x * blockDim.x + threadIdx.x;
  if (t >= n8) return;
  int i = t * 8;
  float f[8];
  if (is_f32(flag)){
    const float4* p = (const float4*)((const float*)in + i);
    float4 a = p[0], b = p[1];
    f[0]=a.x; f[1]=a.y; f[2]=a.z; f[3]=a.w; f[4]=b.x; f[5]=b.y; f[6]=b.z; f[7]=b.w;
  } else {
    uint4 v = *(const uint4*)((const ushort*)in + i);
    const uint* vw = (const uint*)&v;
    #pragma unroll
    for (int p = 0; p < 4; p++){
      f[2*p]   = __uint_as_float(vw[p] << 16);
      f[2*p+1] = __uint_as_float(vw[p] & 0xffff0000u);
    }
  }
  *(float4*)(out + i)     = make_float4(f[0], f[1], f[2], f[3]);
  *(float4*)(out + i + 4) = make_float4(f[4], f[5], f[6], f[7]);
}

// ---------- CSR build: degree count ----------
__global__ void k_deg(const int* __restrict__ dst, int* __restrict__ deg, int Ep){
  int e = blockIdx.x * blockDim.x + threadIdx.x;
  if (e < Ep) atomicAdd(&deg[dst[e]], 1);
}

// ---------- scan 1: per-block inclusive scan + block sums ----------
__global__ __launch_bounds__(256) void k_scan1(const int* __restrict__ deg,
    int* __restrict__ incl, int* __restrict__ bsum, int N){
  __shared__ int tmp[256];
  int i = blockIdx.x * 256 + threadIdx.x;
  int v = (i < N) ? deg[i] : 0;
  tmp[threadIdx.x] = v; __syncthreads();
  for (int o = 1; o < 256; o <<= 1){
    int t = (threadIdx.x >= o) ? tmp[threadIdx.x - o] : 0;
    __syncthreads();
    tmp[threadIdx.x] += t;
    __syncthreads();
  }
  if (i < N) incl[i] = tmp[threadIdx.x];
  if (threadIdx.x == 255) bsum[blockIdx.x] = tmp[255];
}

// ---------- scan 2: serial exclusive scan of block sums (nb ~ 391, trivial) ----------
__global__ void k_scan2(int* __restrict__ bsum, int nb){
  if (blockIdx.x == 0 && threadIdx.x == 0){
    int run = 0;
    for (int i = 0; i < nb; i++){ int v = bsum[i]; bsum[i] = run; run += v; }
  }
}

// ---------- scan 3: rowptr (exclusive) + cursor copy ----------
__global__ void k_scan3(const int* __restrict__ deg, const int* __restrict__ incl,
                        const int* __restrict__ bsum, int* __restrict__ rowptr,
                        int* __restrict__ cursor, int N, int Ep){
  int i = blockIdx.x * 256 + threadIdx.x;
  if (i < N){
    int r = bsum[blockIdx.x] + incl[i] - deg[i];
    rowptr[i] = r; cursor[i] = r;
  }
  if (i == 0) rowptr[N] = Ep;
}

// ---------- fill CSR (order within a row irrelevant) ----------
__global__ void k_fill(const int* __restrict__ src, const int* __restrict__ dst,
                       int* __restrict__ cursor, int* __restrict__ csr_src, int Ep){
  int e = blockIdx.x * blockDim.x + threadIdx.x;
  if (e >= Ep) return;
  int pos = atomicAdd(&cursor[dst[e]], 1);
  csr_src[pos] = src[e];
}

// ---------- GEMM: O[N,M] = X[N,128] @ W[128,M], all f32 ----------
template<int M, int RT>
__global__ __launch_bounds__(256) void k_gemm(const float* __restrict__ X,
    const float* __restrict__ W, float* __restrict__ O, int N){
  constexpr int K = 128;
  __shared__ float Wl[K * M];
  for (int i = threadIdx.x; i < K * M; i += 256) Wl[i] = W[i];
  __syncthreads();
  constexpr int CG = M / 8;
  int cx = threadIdx.x % CG;
  int ry = threadIdx.x / CG;
  int row0 = blockIdx.x * 64 + ry * RT;
  float acc[RT][8];
  #pragma unroll
  for (int r = 0; r < RT; r++)
    #pragma unroll
    for (int c = 0; c < 8; c++) acc[r][c] = 0.f;

  for (int kb = 0; kb < K; kb += 4){
    float4 xv[RT];
    #pragma unroll
    for (int r = 0; r < RT; r++){
      int row = row0 + r; if (row >= N) row = N - 1;
      xv[r] = *(const float4*)(X + (size_t)row * K + kb);
    }
    #pragma unroll
    for (int kk = 0; kk < 4; kk++){
      float wr[8];
      #pragma unroll
      for (int c = 0; c < 8; c++) wr[c] = Wl[(kb + kk) * M + cx * 8 + c];
      #pragma unroll
      for (int r = 0; r < RT; r++){
        float xf = ((const float*)&xv[r])[kk];
        #pragma unroll
        for (int c = 0; c < 8; c++) acc[r][c] = fmaf(xf, wr[c], acc[r][c]);
      }
    }
  }
  #pragma unroll
  for (int r = 0; r < RT; r++){
    int row = row0 + r;
    if (row < N){
      float* op = O + (size_t)row * M + cx * 8;
      *(float4*)(op)     = make_float4(acc[r][0], acc[r][1], acc[r][2], acc[r][3]);
      *(float4*)(op + 4) = make_float4(acc[r][4], acc[r][5], acc[r][6], acc[r][7]);
    }
  }
}

// ---------- per (node,head) attention dots ----------
template<int H>
__global__ void k_att(const float* __restrict__ Hf, const float* __restrict__ attS,
                      const float* __restrict__ attD,
                      float* __restrict__ aS, float* __restrict__ aD, int NH){
  int t = blockIdx.x * blockDim.x + threadIdx.x;
  if (t >= NH) return;
  int h = t % H;
  const float* hp = Hf + (size_t)t * 64;
  float s = 0.f, d = 0.f;
  #pragma unroll
  for (int cb = 0; cb < 64; cb += 4){
    float4 hv = *(const float4*)(hp + cb);
    float4 sv = *(const float4*)(attS + h * 64 + cb);
    float4 dv = *(const float4*)(attD + h * 64 + cb);
    s = fmaf(hv.x, sv.x, s); s = fmaf(hv.y, sv.y, s);
    s = fmaf(hv.z, sv.z, s); s = fmaf(hv.w, sv.w, s);
    d = fmaf(hv.x, dv.x, d); d = fmaf(hv.y, dv.y, d);
    d = fmaf(hv.z, dv.z, d); d = fmaf(hv.w, dv.w, d);
  }
  aS[t] = s; aD[t] = d;
}

// ---------- fused softmax + aggregation: one wave per (dst, head) ----------
// Phase A: lane-parallel online softmax (m,s) over incoming edges + wave combine.
// Phase B: serial edge loop, lane = channel, register accumulate, one store.
// MODE 0: += bias, ELU, write f32 (layer1).  MODE 1: += bias, write per flag (final).
template<int H, int MODE>
__global__ __launch_bounds__(256) void k_agg(const int* __restrict__ rowptr,
    const int* __restrict__ csr_src, const float* __restrict__ aS,
    const float* __restrict__ aD, const float* __restrict__ Hf,
    const float* __restrict__ bias, void* __restrict__ outp, int N,
    const uint* __restrict__ flag){
  int wid  = (blockIdx.x * 256 + threadIdx.x) >> 6;
  int lane = threadIdx.x & 63;
  if (wid >= N * H) return;
  int d = wid / H, h = wid % H;
  int r0 = rowptr[d], r1 = rowptr[d + 1];
  float aDd = aD[d * H + h];

  // ---- phase A: online (m,s) ----
  float m = -1e30f, s = 0.f;          // -1e30 sentinel: -inf breaks the combine (nan)
  for (int j = r0 + lane; j < r1; j += 64){
    int sj = csr_src[j];
    float v = aS[sj * H + h] + aDd;
    v = v > 0.f ? v : 0.2f * v;       // leaky_relu 0.2
    if (v > m){ s = s * __expf(m - v) + 1.f; m = v; }
    else        s += __expf(v - m);
  }
  #pragma unroll
  for (int o = 1; o < 64; o <<= 1){
    float mo = __shfl_xor(m, o), so = __shfl_xor(s, o);
    float M = fmaxf(m, mo);
    s = s * __expf(m - M) + so * __expf(mo - M);
    m = M;
  }
  float inv = 1.f / (s + 1e-16f);

  // ---- phase B: lane = channel ----
  float acc = 0.f;
  for (int j = r0; j < r1; j++){
    int sj = csr_src[j];                       // broadcast load
    float v = aS[sj * H + h] + aDd;            // broadcast load
    v = v > 0.f ? v : 0.2f * v;
    float alpha = __expf(v - m) * inv;
    acc = fmaf(alpha, Hf[((size_t)sj * H + h) * 64 + lane], acc);
  }

  // ---- epilogue ----
  if (MODE == 0){
    int col = h * 64 + lane;
    float o = acc + bias[col];
    o = o > 0.f ? o : expm1f(o);               // ELU
    ((float*)outp)[(size_t)d * (H * 64) + col] = o;
  } else {
    float o = acc + bias[lane];
    if (is_f32(flag)) ((float*)outp)[(size_t)d * 64 + lane] = o;
    else              ((ushort*)outp)[(size_t)d * 64 + lane] = f2bf(o);
  }
}

extern "C" void kernel_launch(void* const* d_in, const int* in_sizes, int n_in,
                              void* d_out, int out_size, void* d_ws, size_t ws_size,
                              hipStream_t stream){
  const void* x   = d_in[0];
  const void* ei  = d_in[1];
  const void* W1  = d_in[2];
  const void* aS1w= d_in[3];
  const void* aD1w= d_in[4];
  const void* b1w = d_in[5];
  const void* W2  = d_in[6];
  const void* aS2w= d_in[7];
  const void* aD2w= d_in[8];
  const void* b2w = d_in[9];

  const int N  = in_sizes[0] / 128;
  const int E  = in_sizes[1] / 2;
  const int Ep = E + N;
  const int nb = (N + 255) / 256;

  char* w = (char*)d_ws;
  size_t off = 0;
  auto alloc = [&](size_t bytes)->char*{
    char* p = w + off; off = (off + bytes + 255) & ~(size_t)255; return p;
  };
  uint*  flag   = (uint*) alloc(256);
  int*   src32  = (int*)  alloc((size_t)Ep * 4);
  int*   dst32  = (int*)  alloc((size_t)Ep * 4);
  int*   csr    = (int*)  alloc((size_t)Ep * 4);
  int*   deg    = (int*)  alloc((size_t)N * 4);
  int*   incl   = (int*)  alloc((size_t)N * 4);
  int*   rowptr = (int*)  alloc((size_t)(N + 1) * 4);
  int*   cursor = (int*)  alloc((size_t)N * 4);
  int*   bsum   = (int*)  alloc((size_t)nb * 4);
  float* Wf1    = (float*)alloc((size_t)128 * 128 * 4);
  float* aSf1   = (float*)alloc(128 * 4);
  float* aDf1   = (float*)alloc(128 * 4);
  float* bf1    = (float*)alloc(128 * 4);
  float* Wf2    = (float*)alloc((size_t)128 * 64 * 4);
  float* aSf2   = (float*)alloc(64 * 4);
  float* aDf2   = (float*)alloc(64 * 4);
  float* bf2    = (float*)alloc(64 * 4);
  float* aS1    = (float*)alloc((size_t)N * 2 * 4);
  float* aD1    = (float*)alloc((size_t)N * 2 * 4);
  float* aS2    = (float*)alloc((size_t)N * 4);
  float* aD2    = (float*)alloc((size_t)N * 4);
  float* A      = (float*)alloc((size_t)N * 128 * 4);  // xf -> h1(post-ELU)
  float* B      = (float*)alloc((size_t)N * 128 * 4);  // h (pre-attention) per layer

  hipMemsetAsync(flag, 0, 8, stream);
  hipMemsetAsync(deg, 0, (size_t)N * 4, stream);

  k_detect_edge<<<512, 256, 0, stream>>>((const uint*)ei, 2 * E, flag);
  k_detect_f32 <<<512, 256, 0, stream>>>((const uint*)x, 1 << 20, flag);

  int gbE = (Ep + 255) / 256;
  k_convert<<<gbE, 256, 0, stream>>>(ei, E, Ep, flag, src32, dst32);

  // ---- CSR build (shared by both layers) ----
  k_deg  <<<gbE, 256, 0, stream>>>(dst32, deg, Ep);
  k_scan1<<<nb, 256, 0, stream>>>(deg, incl, bsum, N);
  k_scan2<<<1, 64, 0, stream>>>(bsum, nb);
  k_scan3<<<nb, 256, 0, stream>>>(deg, incl, bsum, rowptr, cursor, N, Ep);
  k_fill <<<gbE, 256, 0, stream>>>(src32, dst32, cursor, csr, Ep);

  // ---- normalize float tensors to f32 ----
  auto cvt = [&](const void* in, float* outp, int n){
    int n8 = n / 8;
    k_cvt<<<(n8 + 255) / 256, 256, 0, stream>>>(in, outp, n8, flag);
  };
  cvt(x,    A,    N * 128);
  cvt(W1,   Wf1,  128 * 128);
  cvt(aS1w, aSf1, 128);
  cvt(aD1w, aDf1, 128);
  cvt(b1w,  bf1,  128);
  cvt(W2,   Wf2,  128 * 64);
  cvt(aS2w, aSf2, 64);
  cvt(aD2w, aDf2, 64);
  cvt(b2w,  bf2,  64);

  int gemmb = (N + 63) / 64;
  // -------- layer 1 (H=2): gemm -> att -> fused agg(+bias+ELU) --------
  k_gemm<128, 4><<<gemmb, 256, 0, stream>>>(A, Wf1, B, N);
  k_att<2><<<(N * 2 + 255) / 256, 256, 0, stream>>>(B, aSf1, aDf1, aS1, aD1, N * 2);
  {
    int waves = N * 2, blocks = (waves * 64 + 255) / 256;
    k_agg<2, 0><<<blocks, 256, 0, stream>>>(rowptr, csr, aS1, aD1, B, bf1, A, N, flag);
  }
  // -------- layer 2 (H=1): gemm -> att -> fused agg(+bias) --------
  k_gemm<64, 2><<<gemmb, 256, 0, stream>>>(A, Wf2, B, N);
  k_att<1><<<(N + 255) / 256, 256, 0, stream>>>(B, aSf2, aDf2, aS2, aD2, N);
  {
    int waves = N, blocks = (waves * 64 + 255) / 256;
    k_agg<1, 1><<<blocks, 256, 0, stream>>>(rowptr, csr, aS2, aD2, B, bf2, d_out, N, flag);
  }
}

// Round 6
// 795.327 us; speedup vs baseline: 12.2726x; 1.3303x over previous
//
#include <hip/hip_runtime.h>

typedef unsigned int uint;
typedef unsigned short ushort;

// ---------- helpers ----------
__device__ __forceinline__ ushort f2bf(float f){            // RTNE
  uint u = __float_as_uint(f);
  u += 0x7fffu + ((u >> 16) & 1u);
  return (ushort)(u >> 16);
}
__device__ __forceinline__ bool is_f32(const uint* __restrict__ flag){ return flag[1] > 4096u; }
__device__ __forceinline__ float leaky(float v){ return v > 0.f ? v : 0.2f * v; }

// ---------- edge dtype detect ----------
__global__ void k_detect_edge(const uint* __restrict__ w, int nwords, uint* __restrict__ flag){
  uint v = 0;
  for (int i = blockIdx.x * blockDim.x + threadIdx.x; 2 * i + 1 < nwords;
       i += gridDim.x * blockDim.x)
    v |= w[2 * i + 1];
  #pragma unroll
  for (int o = 32; o > 0; o >>= 1) v |= __shfl_xor(v, o);
  if ((threadIdx.x & 63) == 0 && v) atomicOr(&flag[0], 1u);
}

// ---------- float dtype detect on x ----------
__global__ void k_detect_f32(const uint* __restrict__ w, int nwords, uint* __restrict__ flag){
  uint c = 0;
  for (int i = blockIdx.x * blockDim.x + threadIdx.x; i < nwords;
       i += gridDim.x * blockDim.x){
    uint eb = (w[i] >> 7) & 0xFFu;
    c += (eb >= 0xC0u) ? 1u : 0u;
  }
  #pragma unroll
  for (int o = 32; o > 0; o >>= 1) c += __shfl_xor(c, o);
  if ((threadIdx.x & 63) == 0 && c) atomicAdd(&flag[1], c);
}

// ---------- convert edge_index (+self loops) to int32 src/dst ----------
__global__ void k_convert(const void* __restrict__ ei, int E, int Ep,
                          const uint* __restrict__ flag,
                          int* __restrict__ src, int* __restrict__ dst){
  int e = blockIdx.x * blockDim.x + threadIdx.x;
  if (e >= Ep) return;
  if (e >= E){ src[e] = e - E; dst[e] = e - E; return; }
  if (flag[0]){
    const int* p = (const int*)ei;
    src[e] = p[e]; dst[e] = p[(size_t)E + e];
  } else {
    const long long* p = (const long long*)ei;
    src[e] = (int)p[e]; dst[e] = (int)p[(size_t)E + e];
  }
}

// ---------- normalize float tensor (f32 or packed bf16) -> f32 ----------
__device__ __forceinline__ void cvt8(const void* __restrict__ in, float* __restrict__ out,
                                     int i, bool f32){
  float f[8];
  if (f32){
    const float4* p = (const float4*)((const float*)in + i);
    float4 a = p[0], b = p[1];
    f[0]=a.x; f[1]=a.y; f[2]=a.z; f[3]=a.w; f[4]=b.x; f[5]=b.y; f[6]=b.z; f[7]=b.w;
  } else {
    uint4 v = *(const uint4*)((const ushort*)in + i);
    const uint* vw = (const uint*)&v;
    #pragma unroll
    for (int p = 0; p < 4; p++){
      f[2*p]   = __uint_as_float(vw[p] << 16);
      f[2*p+1] = __uint_as_float(vw[p] & 0xffff0000u);
    }
  }
  *(float4*)(out + i)     = make_float4(f[0], f[1], f[2], f[3]);
  *(float4*)(out + i + 4) = make_float4(f[4], f[5], f[6], f[7]);
}

__global__ void k_cvt(const void* __restrict__ in, float* __restrict__ out, int n8,
                      const uint* __restrict__ flag){
  int t = blockIdx.x * blockDim.x + threadIdx.x;
  if (t >= n8) return;
  cvt8(in, out, t * 8, is_f32(flag));
}

// all 8 small param tensors in one launch
struct CvtArgs { const void* src[8]; float* dst[8]; int n8[8]; int total8; };
__global__ void k_cvt8(CvtArgs a, const uint* __restrict__ flag){
  int t = blockIdx.x * blockDim.x + threadIdx.x;
  if (t >= a.total8) return;
  int seg = 0, off = t;
  #pragma unroll
  for (int s = 0; s < 8; s++){
    if (off >= a.n8[seg]) { off -= a.n8[seg]; seg++; } else break;
  }
  cvt8(a.src[seg], a.dst[seg], off * 8, is_f32(flag));
}

// ---------- CSR build ----------
__global__ void k_deg(const int* __restrict__ dst, int* __restrict__ deg, int Ep){
  int e = blockIdx.x * blockDim.x + threadIdx.x;
  if (e < Ep) atomicAdd(&deg[dst[e]], 1);
}

__global__ __launch_bounds__(256) void k_scan1(const int* __restrict__ deg,
    int* __restrict__ incl, int* __restrict__ bsum, int N){
  __shared__ int tmp[256];
  int i = blockIdx.x * 256 + threadIdx.x;
  int v = (i < N) ? deg[i] : 0;
  tmp[threadIdx.x] = v; __syncthreads();
  for (int o = 1; o < 256; o <<= 1){
    int t = (threadIdx.x >= o) ? tmp[threadIdx.x - o] : 0;
    __syncthreads();
    tmp[threadIdx.x] += t;
    __syncthreads();
  }
  if (i < N) incl[i] = tmp[threadIdx.x];
  if (threadIdx.x == 255) bsum[blockIdx.x] = tmp[255];
}

__global__ void k_scan2(int* __restrict__ bsum, int nb){
  if (blockIdx.x == 0 && threadIdx.x == 0){
    int run = 0;
    for (int i = 0; i < nb; i++){ int v = bsum[i]; bsum[i] = run; run += v; }
  }
}

__global__ void k_scan3(const int* __restrict__ deg, const int* __restrict__ incl,
                        const int* __restrict__ bsum, int* __restrict__ rowptr,
                        int* __restrict__ cursor, int N, int Ep){
  int i = blockIdx.x * 256 + threadIdx.x;
  if (i < N){
    int r = bsum[blockIdx.x] + incl[i] - deg[i];
    rowptr[i] = r; cursor[i] = r;
  }
  if (i == 0) rowptr[N] = Ep;
}

__global__ void k_fill(const int* __restrict__ src, const int* __restrict__ dst,
                       int* __restrict__ cursor, int* __restrict__ csr_src, int Ep){
  int e = blockIdx.x * blockDim.x + threadIdx.x;
  if (e >= Ep) return;
  int pos = atomicAdd(&cursor[dst[e]], 1);
  csr_src[pos] = src[e];
}

// ---------- GEMM: O[N,M] = X[N,128] @ W[128,M], all f32 ----------
template<int M, int RT>
__global__ __launch_bounds__(256) void k_gemm(const float* __restrict__ X,
    const float* __restrict__ W, float* __restrict__ O, int N){
  constexpr int K = 128;
  __shared__ float Wl[K * M];
  for (int i = threadIdx.x; i < K * M; i += 256) Wl[i] = W[i];
  __syncthreads();
  constexpr int CG = M / 8;
  int cx = threadIdx.x % CG;
  int ry = threadIdx.x / CG;
  int row0 = blockIdx.x * 64 + ry * RT;
  float acc[RT][8];
  #pragma unroll
  for (int r = 0; r < RT; r++)
    #pragma unroll
    for (int c = 0; c < 8; c++) acc[r][c] = 0.f;

  for (int kb = 0; kb < K; kb += 4){
    float4 xv[RT];
    #pragma unroll
    for (int r = 0; r < RT; r++){
      int row = row0 + r; if (row >= N) row = N - 1;
      xv[r] = *(const float4*)(X + (size_t)row * K + kb);
    }
    #pragma unroll
    for (int kk = 0; kk < 4; kk++){
      float wr[8];
      #pragma unroll
      for (int c = 0; c < 8; c++) wr[c] = Wl[(kb + kk) * M + cx * 8 + c];
      #pragma unroll
      for (int r = 0; r < RT; r++){
        float xf = ((const float*)&xv[r])[kk];
        #pragma unroll
        for (int c = 0; c < 8; c++) acc[r][c] = fmaf(xf, wr[c], acc[r][c]);
      }
    }
  }
  #pragma unroll
  for (int r = 0; r < RT; r++){
    int row = row0 + r;
    if (row < N){
      float* op = O + (size_t)row * M + cx * 8;
      *(float4*)(op)     = make_float4(acc[r][0], acc[r][1], acc[r][2], acc[r][3]);
      *(float4*)(op + 4) = make_float4(acc[r][4], acc[r][5], acc[r][6], acc[r][7]);
    }
  }
}

// ---------- per (node,head) attention dots ----------
template<int H>
__global__ void k_att(const float* __restrict__ Hf, const float* __restrict__ attS,
                      const float* __restrict__ attD,
                      float* __restrict__ aS, float* __restrict__ aD, int NH){
  int t = blockIdx.x * blockDim.x + threadIdx.x;
  if (t >= NH) return;
  int h = t % H;
  const float* hp = Hf + (size_t)t * 64;
  float s = 0.f, d = 0.f;
  #pragma unroll
  for (int cb = 0; cb < 64; cb += 4){
    float4 hv = *(const float4*)(hp + cb);
    float4 sv = *(const float4*)(attS + h * 64 + cb);
    float4 dv = *(const float4*)(attD + h * 64 + cb);
    s = fmaf(hv.x, sv.x, s); s = fmaf(hv.y, sv.y, s);
    s = fmaf(hv.z, sv.z, s); s = fmaf(hv.w, sv.w, s);
    d = fmaf(hv.x, dv.x, d); d = fmaf(hv.y, dv.y, d);
    d = fmaf(hv.z, dv.z, d); d = fmaf(hv.w, dv.w, d);
  }
  aS[t] = s; aD[t] = d;
}

// ---------- layer-1 fused agg, H=2 head-merged: one wave per dst ----------
// lane l: channels (2(l&31), 2(l&31)+1) of head l>>5. Hf2 row = 64 float2 (both heads).
// Fast path (deg<=64): lane e owns edge e; alphas in registers; phase B = shfl broadcast.
__global__ __launch_bounds__(256) void k_agg2(const int* __restrict__ rowptr,
    const int* __restrict__ csr_src, const float* __restrict__ aS,
    const float* __restrict__ aD, const float2* __restrict__ Hf2,
    const float2* __restrict__ bias2, float2* __restrict__ out2, int N){
  int wid  = (blockIdx.x * 256 + threadIdx.x) >> 6;
  int lane = threadIdx.x & 63;
  if (wid >= N) return;
  int d = wid;
  int r0 = rowptr[d], r1 = rowptr[d + 1];
  int cnt = r1 - r0;
  float aD0 = aD[d * 2], aD1 = aD[d * 2 + 1];
  float2 acc = make_float2(0.f, 0.f);

  if (cnt <= 64){
    int   sj = 0;
    float v0 = -1e30f, v1 = -1e30f;
    if (lane < cnt){
      sj = csr_src[r0 + lane];
      v0 = leaky(aS[sj * 2]     + aD0);
      v1 = leaky(aS[sj * 2 + 1] + aD1);
    }
    float M0 = v0, M1 = v1;
    #pragma unroll
    for (int o = 1; o < 64; o <<= 1){
      M0 = fmaxf(M0, __shfl_xor(M0, o));
      M1 = fmaxf(M1, __shfl_xor(M1, o));
    }
    float e0 = (lane < cnt) ? __expf(v0 - M0) : 0.f;
    float e1 = (lane < cnt) ? __expf(v1 - M1) : 0.f;
    float S0 = e0, S1 = e1;
    #pragma unroll
    for (int o = 1; o < 64; o <<= 1){
      S0 += __shfl_xor(S0, o);
      S1 += __shfl_xor(S1, o);
    }
    float a0 = e0 / (S0 + 1e-16f);
    float a1 = e1 / (S1 + 1e-16f);
    for (int i = 0; i < cnt; i++){
      int   sb = __shfl(sj, i);
      float b0 = __shfl(a0, i);
      float b1 = __shfl(a1, i);
      float ah = (lane < 32) ? b0 : b1;
      float2 hv = Hf2[(size_t)sb * 64 + lane];
      acc.x = fmaf(ah, hv.x, acc.x);
      acc.y = fmaf(ah, hv.y, acc.y);
    }
  } else {
    // slow path: online (m,s) per lane over strided edges, combine, serial recompute
    float m0 = -1e30f, s0 = 0.f, m1 = -1e30f, s1 = 0.f;
    for (int j = r0 + lane; j < r1; j += 64){
      int sj = csr_src[j];
      float v0 = leaky(aS[sj * 2]     + aD0);
      float v1 = leaky(aS[sj * 2 + 1] + aD1);
      if (v0 > m0){ s0 = s0 * __expf(m0 - v0) + 1.f; m0 = v0; } else s0 += __expf(v0 - m0);
      if (v1 > m1){ s1 = s1 * __expf(m1 - v1) + 1.f; m1 = v1; } else s1 += __expf(v1 - m1);
    }
    #pragma unroll
    for (int o = 1; o < 64; o <<= 1){
      float mo = __shfl_xor(m0, o), so = __shfl_xor(s0, o);
      float M = fmaxf(m0, mo);
      s0 = s0 * __expf(m0 - M) + so * __expf(mo - M); m0 = M;
      mo = __shfl_xor(m1, o); so = __shfl_xor(s1, o);
      M = fmaxf(m1, mo);
      s1 = s1 * __expf(m1 - M) + so * __expf(mo - M); m1 = M;
    }
    float inv0 = 1.f / (s0 + 1e-16f), inv1 = 1.f / (s1 + 1e-16f);
    for (int j = r0; j < r1; j++){
      int sj = csr_src[j];
      float al0 = __expf(leaky(aS[sj * 2]     + aD0) - m0) * inv0;
      float al1 = __expf(leaky(aS[sj * 2 + 1] + aD1) - m1) * inv1;
      float ah = (lane < 32) ? al0 : al1;
      float2 hv = Hf2[(size_t)sj * 64 + lane];
      acc.x = fmaf(ah, hv.x, acc.x);
      acc.y = fmaf(ah, hv.y, acc.y);
    }
  }

  // epilogue: bias + ELU, write f32 (layer-2 input)
  float2 b = bias2[lane];
  float o0 = acc.x + b.x, o1 = acc.y + b.y;
  o0 = o0 > 0.f ? o0 : expm1f(o0);
  o1 = o1 > 0.f ? o1 : expm1f(o1);
  out2[(size_t)d * 64 + lane] = make_float2(o0, o1);
}

// ---------- layer-2 fused agg, H=1: one wave per dst, lane = channel ----------
__global__ __launch_bounds__(256) void k_agg1(const int* __restrict__ rowptr,
    const int* __restrict__ csr_src, const float* __restrict__ aS,
    const float* __restrict__ aD, const float* __restrict__ Hf,
    const float* __restrict__ bias, void* __restrict__ outp, int N,
    const uint* __restrict__ flag){
  int wid  = (blockIdx.x * 256 + threadIdx.x) >> 6;
  int lane = threadIdx.x & 63;
  if (wid >= N) return;
  int d = wid;
  int r0 = rowptr[d], r1 = rowptr[d + 1];
  int cnt = r1 - r0;
  float aDd = aD[d];
  float acc = 0.f;

  if (cnt <= 64){
    int   sj = 0;
    float v = -1e30f;
    if (lane < cnt){
      sj = csr_src[r0 + lane];
      v = leaky(aS[sj] + aDd);
    }
    float M = v;
    #pragma unroll
    for (int o = 1; o < 64; o <<= 1) M = fmaxf(M, __shfl_xor(M, o));
    float e = (lane < cnt) ? __expf(v - M) : 0.f;
    float S = e;
    #pragma unroll
    for (int o = 1; o < 64; o <<= 1) S += __shfl_xor(S, o);
    float a = e / (S + 1e-16f);
    for (int i = 0; i < cnt; i++){
      int   sb = __shfl(sj, i);
      float ab = __shfl(a, i);
      acc = fmaf(ab, Hf[(size_t)sb * 64 + lane], acc);
    }
  } else {
    float m = -1e30f, s = 0.f;
    for (int j = r0 + lane; j < r1; j += 64){
      int sj = csr_src[j];
      float v = leaky(aS[sj] + aDd);
      if (v > m){ s = s * __expf(m - v) + 1.f; m = v; } else s += __expf(v - m);
    }
    #pragma unroll
    for (int o = 1; o < 64; o <<= 1){
      float mo = __shfl_xor(m, o), so = __shfl_xor(s, o);
      float M = fmaxf(m, mo);
      s = s * __expf(m - M) + so * __expf(mo - M); m = M;
    }
    float inv = 1.f / (s + 1e-16f);
    for (int j = r0; j < r1; j++){
      int sj = csr_src[j];
      float al = __expf(leaky(aS[sj] + aDd) - m) * inv;
      acc = fmaf(al, Hf[(size_t)sj * 64 + lane], acc);
    }
  }

  float o = acc + bias[lane];
  if (is_f32(flag)) ((float*)outp)[(size_t)d * 64 + lane] = o;
  else              ((ushort*)outp)[(size_t)d * 64 + lane] = f2bf(o);
}

extern "C" void kernel_launch(void* const* d_in, const int* in_sizes, int n_in,
                              void* d_out, int out_size, void* d_ws, size_t ws_size,
                              hipStream_t stream){
  const void* x   = d_in[0];
  const void* ei  = d_in[1];
  const void* W1  = d_in[2];
  const void* aS1w= d_in[3];
  const void* aD1w= d_in[4];
  const void* b1w = d_in[5];
  const void* W2  = d_in[6];
  const void* aS2w= d_in[7];
  const void* aD2w= d_in[8];
  const void* b2w = d_in[9];

  const int N  = in_sizes[0] / 128;
  const int E  = in_sizes[1] / 2;
  const int Ep = E + N;
  const int nb = (N + 255) / 256;

  char* w = (char*)d_ws;
  size_t off = 0;
  auto alloc = [&](size_t bytes)->char*{
    char* p = w + off; off = (off + bytes + 255) & ~(size_t)255; return p;
  };
  uint*  flag   = (uint*) alloc(256);
  int*   src32  = (int*)  alloc((size_t)Ep * 4);
  int*   dst32  = (int*)  alloc((size_t)Ep * 4);
  int*   csr    = (int*)  alloc((size_t)Ep * 4);
  int*   deg    = (int*)  alloc((size_t)N * 4);
  int*   incl   = (int*)  alloc((size_t)N * 4);
  int*   rowptr = (int*)  alloc((size_t)(N + 1) * 4);
  int*   cursor = (int*)  alloc((size_t)N * 4);
  int*   bsum   = (int*)  alloc((size_t)nb * 4);
  float* Wf1    = (float*)alloc((size_t)128 * 128 * 4);
  float* aSf1   = (float*)alloc(128 * 4);
  float* aDf1   = (float*)alloc(128 * 4);
  float* bf1    = (float*)alloc(128 * 4);
  float* Wf2    = (float*)alloc((size_t)128 * 64 * 4);
  float* aSf2   = (float*)alloc(64 * 4);
  float* aDf2   = (float*)alloc(64 * 4);
  float* bf2    = (float*)alloc(64 * 4);
  float* aS1    = (float*)alloc((size_t)N * 2 * 4);
  float* aD1    = (float*)alloc((size_t)N * 2 * 4);
  float* aS2    = (float*)alloc((size_t)N * 4);
  float* aD2    = (float*)alloc((size_t)N * 4);
  float* A      = (float*)alloc((size_t)N * 128 * 4);  // xf -> h1(post-ELU)
  float* B      = (float*)alloc((size_t)N * 128 * 4);  // h (pre-attention) per layer

  hipMemsetAsync(flag, 0, 8, stream);
  hipMemsetAsync(deg, 0, (size_t)N * 4, stream);

  k_detect_edge<<<512, 256, 0, stream>>>((const uint*)ei, 2 * E, flag);
  k_detect_f32 <<<512, 256, 0, stream>>>((const uint*)x, 1 << 20, flag);

  int gbE = (Ep + 255) / 256;
  k_convert<<<gbE, 256, 0, stream>>>(ei, E, Ep, flag, src32, dst32);

  // ---- CSR build (shared by both layers) ----
  k_deg  <<<gbE, 256, 0, stream>>>(dst32, deg, Ep);
  k_scan1<<<nb, 256, 0, stream>>>(deg, incl, bsum, N);
  k_scan2<<<1, 64, 0, stream>>>(bsum, nb);
  k_scan3<<<nb, 256, 0, stream>>>(deg, incl, bsum, rowptr, cursor, N, Ep);
  k_fill <<<gbE, 256, 0, stream>>>(src32, dst32, cursor, csr, Ep);

  // ---- normalize float tensors to f32 ----
  {
    int n8 = N * 128 / 8;
    k_cvt<<<(n8 + 255) / 256, 256, 0, stream>>>(x, A, n8, flag);
  }
  {
    CvtArgs a;
    a.src[0]=W1;  a.dst[0]=Wf1;  a.n8[0]=128*128/8;
    a.src[1]=W2;  a.dst[1]=Wf2;  a.n8[1]=128*64/8;
    a.src[2]=aS1w;a.dst[2]=aSf1; a.n8[2]=16;
    a.src[3]=aD1w;a.dst[3]=aDf1; a.n8[3]=16;
    a.src[4]=b1w; a.dst[4]=bf1;  a.n8[4]=16;
    a.src[5]=aS2w;a.dst[5]=aSf2; a.n8[5]=8;
    a.src[6]=aD2w;a.dst[6]=aDf2; a.n8[6]=8;
    a.src[7]=b2w; a.dst[7]=bf2;  a.n8[7]=8;
    a.total8 = 128*128/8 + 128*64/8 + 16*3 + 8*3;
    k_cvt8<<<(a.total8 + 255) / 256, 256, 0, stream>>>(a, flag);
  }

  int gemmb = (N + 63) / 64;
  // -------- layer 1 (H=2): gemm -> att -> fused head-merged agg(+bias+ELU) --------
  k_gemm<128, 4><<<gemmb, 256, 0, stream>>>(A, Wf1, B, N);
  k_att<2><<<(N * 2 + 255) / 256, 256, 0, stream>>>(B, aSf1, aDf1, aS1, aD1, N * 2);
  {
    int blocks = (N * 64 + 255) / 256;
    k_agg2<<<blocks, 256, 0, stream>>>(rowptr, csr, aS1, aD1,
                                       (const float2*)B, (const float2*)bf1,
                                       (float2*)A, N);
  }
  // -------- layer 2 (H=1): gemm -> att -> fused agg(+bias) --------
  k_gemm<64, 2><<<gemmb, 256, 0, stream>>>(A, Wf2, B, N);
  k_att<1><<<(N + 255) / 256, 256, 0, stream>>>(B, aSf2, aDf2, aS2, aD2, N);
  {
    int blocks = (N * 64 + 255) / 256;
    k_agg1<<<blocks, 256, 0, stream>>>(rowptr, csr, aS2, aD2, B, bf2, d_out, N, flag);
  }
}

// Round 7
// 704.766 us; speedup vs baseline: 13.8496x; 1.1285x over previous
//
#include <hip/hip_runtime.h>

typedef unsigned int uint;
typedef unsigned short ushort;

// ---------- helpers ----------
__device__ __forceinline__ float bflo(uint u){ return __uint_as_float(u << 16); }
__device__ __forceinline__ float bfhi(uint u){ return __uint_as_float(u & 0xffff0000u); }
__device__ __forceinline__ float bf2f(ushort u){ return __uint_as_float(((uint)u) << 16); }
__device__ __forceinline__ ushort f2bf(float f){            // RTNE
  uint u = __float_as_uint(f);
  u += 0x7fffu + ((u >> 16) & 1u);
  return (ushort)(u >> 16);
}
__device__ __forceinline__ bool is_f32(const uint* __restrict__ flag){ return flag[1] > 4096u; }
__device__ __forceinline__ float leaky(float v){ return v > 0.f ? v : 0.2f * v; }

// ---------- combined dtype detect: blocks<256 edge-int64 probe, >=256 x-f32 probe ----------
__global__ void k_detect(const uint* __restrict__ ew, int enw,
                         const uint* __restrict__ xw, int xnw, uint* __restrict__ flag){
  if (blockIdx.x < 256){
    uint v = 0;
    for (int i = blockIdx.x * 256 + threadIdx.x; 2 * i + 1 < enw; i += 65536)
      v |= ew[2 * i + 1];
    #pragma unroll
    for (int o = 32; o > 0; o >>= 1) v |= __shfl_xor(v, o);
    if ((threadIdx.x & 63) == 0 && v) atomicOr(&flag[0], 1u);
  } else {
    uint c = 0;
    for (int i = (blockIdx.x - 256) * 256 + threadIdx.x; i < xnw; i += 65536){
      uint eb = (xw[i] >> 7) & 0xFFu;
      c += (eb >= 0xC0u) ? 1u : 0u;
    }
    #pragma unroll
    for (int o = 32; o > 0; o >>= 1) c += __shfl_xor(c, o);
    if ((threadIdx.x & 63) == 0 && c) atomicAdd(&flag[1], c);
  }
}

// ---------- convert edge_index (+self loops) to int32 src/dst, fused degree count ----------
__global__ void k_convert(const void* __restrict__ ei, int E, int Ep,
                          const uint* __restrict__ flag,
                          int* __restrict__ src, int* __restrict__ dst,
                          int* __restrict__ deg){
  int e = blockIdx.x * blockDim.x + threadIdx.x;
  if (e >= Ep) return;
  int s, d;
  if (e >= E){ s = e - E; d = e - E; }
  else if (flag[0]){
    const int* p = (const int*)ei;
    s = p[e]; d = p[(size_t)E + e];
  } else {
    const long long* p = (const long long*)ei;
    s = (int)p[e]; d = (int)p[(size_t)E + e];
  }
  src[e] = s; dst[e] = d;
  atomicAdd(&deg[d], 1);
}

// ---------- normalize float tensor (f32 or packed bf16) -> f32 ----------
__device__ __forceinline__ void cvt8(const void* __restrict__ in, float* __restrict__ out,
                                     int i, bool f32){
  float f[8];
  if (f32){
    const float4* p = (const float4*)((const float*)in + i);
    float4 a = p[0], b = p[1];
    f[0]=a.x; f[1]=a.y; f[2]=a.z; f[3]=a.w; f[4]=b.x; f[5]=b.y; f[6]=b.z; f[7]=b.w;
  } else {
    uint4 v = *(const uint4*)((const ushort*)in + i);
    const uint* vw = (const uint*)&v;
    #pragma unroll
    for (int p = 0; p < 4; p++){
      f[2*p]   = __uint_as_float(vw[p] << 16);
      f[2*p+1] = __uint_as_float(vw[p] & 0xffff0000u);
    }
  }
  *(float4*)(out + i)     = make_float4(f[0], f[1], f[2], f[3]);
  *(float4*)(out + i + 4) = make_float4(f[4], f[5], f[6], f[7]);
}

// all 8 param tensors in one launch
struct CvtArgs { const void* src[8]; float* dst[8]; int n8[8]; int total8; };
__global__ void k_cvt8(CvtArgs a, const uint* __restrict__ flag){
  int t = blockIdx.x * blockDim.x + threadIdx.x;
  if (t >= a.total8) return;
  int seg = 0, off = t;
  #pragma unroll
  for (int s = 0; s < 8; s++){
    if (off >= a.n8[seg]) { off -= a.n8[seg]; seg++; } else break;
  }
  cvt8(a.src[seg], a.dst[seg], off * 8, is_f32(flag));
}

// ---------- CSR build ----------
__global__ __launch_bounds__(256) void k_scan1(const int* __restrict__ deg,
    int* __restrict__ incl, int* __restrict__ bsum, int N){
  __shared__ int tmp[256];
  int i = blockIdx.x * 256 + threadIdx.x;
  int v = (i < N) ? deg[i] : 0;
  tmp[threadIdx.x] = v; __syncthreads();
  for (int o = 1; o < 256; o <<= 1){
    int t = (threadIdx.x >= o) ? tmp[threadIdx.x - o] : 0;
    __syncthreads();
    tmp[threadIdx.x] += t;
    __syncthreads();
  }
  if (i < N) incl[i] = tmp[threadIdx.x];
  if (threadIdx.x == 255) bsum[blockIdx.x] = tmp[255];
}

// parallel exclusive scan of block sums (nb <= 1024)
__global__ __launch_bounds__(1024) void k_scan2(int* __restrict__ bsum, int nb){
  __shared__ int tmp[1024];
  int t = threadIdx.x;
  int v = (t < nb) ? bsum[t] : 0;
  tmp[t] = v; __syncthreads();
  for (int o = 1; o < 1024; o <<= 1){
    int x = (t >= o) ? tmp[t - o] : 0;
    __syncthreads();
    tmp[t] += x;
    __syncthreads();
  }
  if (t < nb) bsum[t] = tmp[t] - v;     // exclusive
}

__global__ void k_scan2_serial(int* __restrict__ bsum, int nb){
  if (blockIdx.x == 0 && threadIdx.x == 0){
    int run = 0;
    for (int i = 0; i < nb; i++){ int v = bsum[i]; bsum[i] = run; run += v; }
  }
}

__global__ void k_scan3(const int* __restrict__ deg, const int* __restrict__ incl,
                        const int* __restrict__ bsum, int* __restrict__ rowptr,
                        int* __restrict__ cursor, int N, int Ep){
  int i = blockIdx.x * 256 + threadIdx.x;
  if (i < N){
    int r = bsum[blockIdx.x] + incl[i] - deg[i];
    rowptr[i] = r; cursor[i] = r;
  }
  if (i == 0) rowptr[N] = Ep;
}

__global__ void k_fill(const int* __restrict__ src, const int* __restrict__ dst,
                       int* __restrict__ cursor, int* __restrict__ csr_src, int Ep){
  int e = blockIdx.x * blockDim.x + threadIdx.x;
  if (e >= Ep) return;
  int pos = atomicAdd(&cursor[dst[e]], 1);
  csr_src[pos] = src[e];
}

// ---------- GEMM: O[N,M](bf16) = X[N,128] @ W[128,M]; X dtype per mode/flag ----------
// mode 0: X per flag (f32 or bf16).  mode 1: X always f32.
template<int M, int RT>
__global__ __launch_bounds__(256) void k_gemm(const void* __restrict__ X,
    const float* __restrict__ W, ushort* __restrict__ O, int N,
    const uint* __restrict__ flag, int mode){
  constexpr int K = 128;
  __shared__ float Wl[K * M];
  for (int i = threadIdx.x; i < K * M; i += 256) Wl[i] = W[i];
  __syncthreads();
  bool xf32 = (mode == 1) || is_f32(flag);
  constexpr int CG = M / 8;
  int cx = threadIdx.x % CG;
  int ry = threadIdx.x / CG;
  int row0 = blockIdx.x * 64 + ry * RT;
  float acc[RT][8];
  #pragma unroll
  for (int r = 0; r < RT; r++)
    #pragma unroll
    for (int c = 0; c < 8; c++) acc[r][c] = 0.f;

  for (int kb = 0; kb < K; kb += 4){
    float4 xv[RT];
    #pragma unroll
    for (int r = 0; r < RT; r++){
      int row = row0 + r; if (row >= N) row = N - 1;
      if (xf32){
        xv[r] = *(const float4*)((const float*)X + (size_t)row * K + kb);
      } else {
        uint2 u = *(const uint2*)((const ushort*)X + (size_t)row * K + kb);
        xv[r] = make_float4(bflo(u.x), bfhi(u.x), bflo(u.y), bfhi(u.y));
      }
    }
    #pragma unroll
    for (int kk = 0; kk < 4; kk++){
      float wr[8];
      #pragma unroll
      for (int c = 0; c < 8; c++) wr[c] = Wl[(kb + kk) * M + cx * 8 + c];
      #pragma unroll
      for (int r = 0; r < RT; r++){
        float xf = ((const float*)&xv[r])[kk];
        #pragma unroll
        for (int c = 0; c < 8; c++) acc[r][c] = fmaf(xf, wr[c], acc[r][c]);
      }
    }
  }
  #pragma unroll
  for (int r = 0; r < RT; r++){
    int row = row0 + r;
    if (row < N){
      uint4 o; uint* ow = (uint*)&o;
      #pragma unroll
      for (int p = 0; p < 4; p++)
        ow[p] = (uint)f2bf(acc[r][2 * p]) | ((uint)f2bf(acc[r][2 * p + 1]) << 16);
      *(uint4*)(O + (size_t)row * M + cx * 8) = o;
    }
  }
}

// ---------- per (node,head) attention dots (bf16 h) ----------
template<int H>
__global__ void k_att(const ushort* __restrict__ Hb, const float* __restrict__ attS,
                      const float* __restrict__ attD,
                      float* __restrict__ aS, float* __restrict__ aD, int NH){
  int t = blockIdx.x * blockDim.x + threadIdx.x;
  if (t >= NH) return;
  int h = t % H;
  const ushort* hp = Hb + (size_t)t * 64;
  float s = 0.f, d = 0.f;
  #pragma unroll
  for (int cb = 0; cb < 64; cb += 8){
    uint4 hv = *(const uint4*)(hp + cb);
    const uint* hw = (const uint*)&hv;
    float4 sv0 = *(const float4*)(attS + h * 64 + cb);
    float4 sv1 = *(const float4*)(attS + h * 64 + cb + 4);
    float4 dv0 = *(const float4*)(attD + h * 64 + cb);
    float4 dv1 = *(const float4*)(attD + h * 64 + cb + 4);
    const float* sw = (const float*)&sv0; const float* sw1 = (const float*)&sv1;
    const float* dw = (const float*)&dv0; const float* dw1 = (const float*)&dv1;
    #pragma unroll
    for (int p = 0; p < 4; p++){
      float h0 = bflo(hw[p]), h1 = bfhi(hw[p]);
      float sa = (p < 2) ? sw[2*p]   : sw1[2*p-4];
      float sb = (p < 2) ? sw[2*p+1] : sw1[2*p-3];
      float da = (p < 2) ? dw[2*p]   : dw1[2*p-4];
      float db = (p < 2) ? dw[2*p+1] : dw1[2*p-3];
      s = fmaf(h0, sa, s); s = fmaf(h1, sb, s);
      d = fmaf(h0, da, d); d = fmaf(h1, db, d);
    }
  }
  aS[t] = s; aD[t] = d;
}

// ---------- layer-1 fused agg, H=2 head-merged, bf16 h: one wave per dst ----------
// h row = 128 bf16 = 64 uints; lane l reads uint l = channels (2(l&31), 2(l&31)+1) of head l>>5.
__global__ __launch_bounds__(256) void k_agg2(const int* __restrict__ rowptr,
    const int* __restrict__ csr_src, const float* __restrict__ aS,
    const float* __restrict__ aD, const ushort* __restrict__ Hb,
    const float2* __restrict__ bias2, float2* __restrict__ out2, int N){
  const uint* Hrow = (const uint*)Hb;
  int wid  = (blockIdx.x * 256 + threadIdx.x) >> 6;
  int lane = threadIdx.x & 63;
  if (wid >= N) return;
  int d = wid;
  int r0 = rowptr[d], r1 = rowptr[d + 1];
  int cnt = r1 - r0;
  float aD0 = aD[d * 2], aD1 = aD[d * 2 + 1];
  float2 acc = make_float2(0.f, 0.f);

  if (cnt <= 64){
    int   sj = 0;
    float v0 = -1e30f, v1 = -1e30f;
    if (lane < cnt){
      sj = csr_src[r0 + lane];
      v0 = leaky(aS[sj * 2]     + aD0);
      v1 = leaky(aS[sj * 2 + 1] + aD1);
    }
    float M0 = v0, M1 = v1;
    #pragma unroll
    for (int o = 1; o < 64; o <<= 1){
      M0 = fmaxf(M0, __shfl_xor(M0, o));
      M1 = fmaxf(M1, __shfl_xor(M1, o));
    }
    float e0 = (lane < cnt) ? __expf(v0 - M0) : 0.f;
    float e1 = (lane < cnt) ? __expf(v1 - M1) : 0.f;
    float S0 = e0, S1 = e1;
    #pragma unroll
    for (int o = 1; o < 64; o <<= 1){
      S0 += __shfl_xor(S0, o);
      S1 += __shfl_xor(S1, o);
    }
    float a0 = e0 / (S0 + 1e-16f);
    float a1 = e1 / (S1 + 1e-16f);
    for (int i = 0; i < cnt; i++){
      int   sb = __shfl(sj, i);
      float b0 = __shfl(a0, i);
      float b1 = __shfl(a1, i);
      float ah = (lane < 32) ? b0 : b1;
      uint hv = Hrow[(size_t)sb * 64 + lane];
      acc.x = fmaf(ah, bflo(hv), acc.x);
      acc.y = fmaf(ah, bfhi(hv), acc.y);
    }
  } else {
    float m0 = -1e30f, s0 = 0.f, m1 = -1e30f, s1 = 0.f;
    for (int j = r0 + lane; j < r1; j += 64){
      int sj = csr_src[j];
      float v0 = leaky(aS[sj * 2]     + aD0);
      float v1 = leaky(aS[sj * 2 + 1] + aD1);
      if (v0 > m0){ s0 = s0 * __expf(m0 - v0) + 1.f; m0 = v0; } else s0 += __expf(v0 - m0);
      if (v1 > m1){ s1 = s1 * __expf(m1 - v1) + 1.f; m1 = v1; } else s1 += __expf(v1 - m1);
    }
    #pragma unroll
    for (int o = 1; o < 64; o <<= 1){
      float mo = __shfl_xor(m0, o), so = __shfl_xor(s0, o);
      float M = fmaxf(m0, mo);
      s0 = s0 * __expf(m0 - M) + so * __expf(mo - M); m0 = M;
      mo = __shfl_xor(m1, o); so = __shfl_xor(s1, o);
      M = fmaxf(m1, mo);
      s1 = s1 * __expf(m1 - M) + so * __expf(mo - M); m1 = M;
    }
    float inv0 = 1.f / (s0 + 1e-16f), inv1 = 1.f / (s1 + 1e-16f);
    for (int j = r0; j < r1; j++){
      int sj = csr_src[j];
      float al0 = __expf(leaky(aS[sj * 2]     + aD0) - m0) * inv0;
      float al1 = __expf(leaky(aS[sj * 2 + 1] + aD1) - m1) * inv1;
      float ah = (lane < 32) ? al0 : al1;
      uint hv = Hrow[(size_t)sj * 64 + lane];
      acc.x = fmaf(ah, bflo(hv), acc.x);
      acc.y = fmaf(ah, bfhi(hv), acc.y);
    }
  }

  float2 b = bias2[lane];
  float o0 = acc.x + b.x, o1 = acc.y + b.y;
  o0 = o0 > 0.f ? o0 : expm1f(o0);
  o1 = o1 > 0.f ? o1 : expm1f(o1);
  out2[(size_t)d * 64 + lane] = make_float2(o0, o1);
}

// ---------- layer-2 fused agg, H=1, bf16 h: one wave per dst, lane = channel ----------
__global__ __launch_bounds__(256) void k_agg1(const int* __restrict__ rowptr,
    const int* __restrict__ csr_src, const float* __restrict__ aS,
    const float* __restrict__ aD, const ushort* __restrict__ Hb,
    const float* __restrict__ bias, void* __restrict__ outp, int N,
    const uint* __restrict__ flag){
  int wid  = (blockIdx.x * 256 + threadIdx.x) >> 6;
  int lane = threadIdx.x & 63;
  if (wid >= N) return;
  int d = wid;
  int r0 = rowptr[d], r1 = rowptr[d + 1];
  int cnt = r1 - r0;
  float aDd = aD[d];
  float acc = 0.f;

  if (cnt <= 64){
    int   sj = 0;
    float v = -1e30f;
    if (lane < cnt){
      sj = csr_src[r0 + lane];
      v = leaky(aS[sj] + aDd);
    }
    float M = v;
    #pragma unroll
    for (int o = 1; o < 64; o <<= 1) M = fmaxf(M, __shfl_xor(M, o));
    float e = (lane < cnt) ? __expf(v - M) : 0.f;
    float S = e;
    #pragma unroll
    for (int o = 1; o < 64; o <<= 1) S += __shfl_xor(S, o);
    float a = e / (S + 1e-16f);
    for (int i = 0; i < cnt; i++){
      int   sb = __shfl(sj, i);
      float ab = __shfl(a, i);
      acc = fmaf(ab, bf2f(Hb[(size_t)sb * 64 + lane]), acc);
    }
  } else {
    float m = -1e30f, s = 0.f;
    for (int j = r0 + lane; j < r1; j += 64){
      int sj = csr_src[j];
      float v = leaky(aS[sj] + aDd);
      if (v > m){ s = s * __expf(m - v) + 1.f; m = v; } else s += __expf(v - m);
    }
    #pragma unroll
    for (int o = 1; o < 64; o <<= 1){
      float mo = __shfl_xor(m, o), so = __shfl_xor(s, o);
      float M = fmaxf(m, mo);
      s = s * __expf(m - M) + so * __expf(mo - M); m = M;
    }
    float inv = 1.f / (s + 1e-16f);
    for (int j = r0; j < r1; j++){
      int sj = csr_src[j];
      float al = __expf(leaky(aS[sj] + aDd) - m) * inv;
      acc = fmaf(al, bf2f(Hb[(size_t)sj * 64 + lane]), acc);
    }
  }

  float o = acc + bias[lane];
  if (is_f32(flag)) ((float*)outp)[(size_t)d * 64 + lane] = o;
  else              ((ushort*)outp)[(size_t)d * 64 + lane] = f2bf(o);
}

extern "C" void kernel_launch(void* const* d_in, const int* in_sizes, int n_in,
                              void* d_out, int out_size, void* d_ws, size_t ws_size,
                              hipStream_t stream){
  const void* x   = d_in[0];
  const void* ei  = d_in[1];
  const void* W1  = d_in[2];
  const void* aS1w= d_in[3];
  const void* aD1w= d_in[4];
  const void* b1w = d_in[5];
  const void* W2  = d_in[6];
  const void* aS2w= d_in[7];
  const void* aD2w= d_in[8];
  const void* b2w = d_in[9];

  const int N  = in_sizes[0] / 128;
  const int E  = in_sizes[1] / 2;
  const int Ep = E + N;
  const int nb = (N + 255) / 256;

  char* w = (char*)d_ws;
  size_t off = 0;
  auto alloc = [&](size_t bytes)->char*{
    char* p = w + off; off = (off + bytes + 255) & ~(size_t)255; return p;
  };
  uint*  flag   = (uint*) alloc(256);
  int*   src32  = (int*)  alloc((size_t)Ep * 4);
  int*   dst32  = (int*)  alloc((size_t)Ep * 4);
  int*   csr    = (int*)  alloc((size_t)Ep * 4);
  int*   deg    = (int*)  alloc((size_t)N * 4);
  int*   incl   = (int*)  alloc((size_t)N * 4);
  int*   rowptr = (int*)  alloc((size_t)(N + 1) * 4);
  int*   cursor = (int*)  alloc((size_t)N * 4);
  int*   bsum   = (int*)  alloc((size_t)nb * 4);
  float* Wf1    = (float*)alloc((size_t)128 * 128 * 4);
  float* aSf1   = (float*)alloc(128 * 4);
  float* aDf1   = (float*)alloc(128 * 4);
  float* bf1    = (float*)alloc(128 * 4);
  float* Wf2    = (float*)alloc((size_t)128 * 64 * 4);
  float* aSf2   = (float*)alloc(64 * 4);
  float* aDf2   = (float*)alloc(64 * 4);
  float* bf2    = (float*)alloc(64 * 4);
  float* aS1    = (float*)alloc((size_t)N * 2 * 4);
  float* aD1    = (float*)alloc((size_t)N * 2 * 4);
  float* aS2    = (float*)alloc((size_t)N * 4);
  float* aD2    = (float*)alloc((size_t)N * 4);
  float* A      = (float*)alloc((size_t)N * 128 * 4);   // agg2 out (f32) = gemm2 in
  ushort* B     = (ushort*)alloc((size_t)N * 128 * 2);  // h (bf16), both layers

  hipMemsetAsync(flag, 0, 8, stream);
  hipMemsetAsync(deg, 0, (size_t)N * 4, stream);

  k_detect<<<512, 256, 0, stream>>>((const uint*)ei, 2 * E, (const uint*)x, 1 << 20, flag);

  int gbE = (Ep + 255) / 256;
  k_convert<<<gbE, 256, 0, stream>>>(ei, E, Ep, flag, src32, dst32, deg);

  // ---- CSR build (shared by both layers) ----
  k_scan1<<<nb, 256, 0, stream>>>(deg, incl, bsum, N);
  if (nb <= 1024) k_scan2<<<1, 1024, 0, stream>>>(bsum, nb);
  else            k_scan2_serial<<<1, 64, 0, stream>>>(bsum, nb);
  k_scan3<<<nb, 256, 0, stream>>>(deg, incl, bsum, rowptr, cursor, N, Ep);
  k_fill <<<gbE, 256, 0, stream>>>(src32, dst32, cursor, csr, Ep);

  // ---- normalize param tensors to f32 (one launch) ----
  {
    CvtArgs a;
    a.src[0]=W1;  a.dst[0]=Wf1;  a.n8[0]=128*128/8;
    a.src[1]=W2;  a.dst[1]=Wf2;  a.n8[1]=128*64/8;
    a.src[2]=aS1w;a.dst[2]=aSf1; a.n8[2]=16;
    a.src[3]=aD1w;a.dst[3]=aDf1; a.n8[3]=16;
    a.src[4]=b1w; a.dst[4]=bf1;  a.n8[4]=16;
    a.src[5]=aS2w;a.dst[5]=aSf2; a.n8[5]=8;
    a.src[6]=aD2w;a.dst[6]=aDf2; a.n8[6]=8;
    a.src[7]=b2w; a.dst[7]=bf2;  a.n8[7]=8;
    a.total8 = 128*128/8 + 128*64/8 + 16*3 + 8*3;
    k_cvt8<<<(a.total8 + 255) / 256, 256, 0, stream>>>(a, flag);
  }

  int gemmb = (N + 63) / 64;
  // -------- layer 1 (H=2): gemm(x direct) -> att -> head-merged agg(+bias+ELU) --------
  k_gemm<128, 4><<<gemmb, 256, 0, stream>>>(x, Wf1, B, N, flag, 0);
  k_att<2><<<(N * 2 + 255) / 256, 256, 0, stream>>>(B, aSf1, aDf1, aS1, aD1, N * 2);
  {
    int blocks = (N * 64 + 255) / 256;
    k_agg2<<<blocks, 256, 0, stream>>>(rowptr, csr, aS1, aD1, B,
                                       (const float2*)bf1, (float2*)A, N);
  }
  // -------- layer 2 (H=1): gemm(A f32) -> att -> agg(+bias) --------
  k_gemm<64, 2><<<gemmb, 256, 0, stream>>>(A, Wf2, B, N, flag, 1);
  k_att<1><<<(N + 255) / 256, 256, 0, stream>>>(B, aSf2, aDf2, aS2, aD2, N);
  {
    int blocks = (N * 64 + 255) / 256;
    k_agg1<<<blocks, 256, 0, stream>>>(rowptr, csr, aS2, aD2, B, bf2, d_out, N, flag);
  }
}

// Round 8
// 560.463 us; speedup vs baseline: 17.4155x; 1.2575x over previous
//
#include <hip/hip_runtime.h>

typedef unsigned int uint;
typedef unsigned short ushort;

// ---------- helpers ----------
__device__ __forceinline__ float bflo(uint u){ return __uint_as_float(u << 16); }
__device__ __forceinline__ float bfhi(uint u){ return __uint_as_float(u & 0xffff0000u); }
__device__ __forceinline__ float bf2f(ushort u){ return __uint_as_float(((uint)u) << 16); }
__device__ __forceinline__ ushort f2bf(float f){            // RTNE
  uint u = __float_as_uint(f);
  u += 0x7fffu + ((u >> 16) & 1u);
  return (ushort)(u >> 16);
}
__device__ __forceinline__ bool is_f32(const uint* __restrict__ flag){ return flag[1] > 4096u; }
__device__ __forceinline__ float leaky(float v){ return v > 0.f ? v : 0.2f * v; }

// ---------- combined dtype detect (sampled: 64K odd words of ei, 64K words of x) ----------
__global__ void k_detect(const uint* __restrict__ ew, int enw,
                         const uint* __restrict__ xw, int xnw, uint* __restrict__ flag){
  if (blockIdx.x < 16){
    uint v = 0;
    for (int i = blockIdx.x * 256 + threadIdx.x; 2 * i + 1 < enw; i += 4096)
      v |= ew[2 * i + 1];
    #pragma unroll
    for (int o = 32; o > 0; o >>= 1) v |= __shfl_xor(v, o);
    if ((threadIdx.x & 63) == 0 && v) atomicOr(&flag[0], 1u);
  } else {
    uint c = 0;
    for (int i = (blockIdx.x - 16) * 256 + threadIdx.x; i < xnw; i += 4096){
      uint eb = (xw[i] >> 7) & 0xFFu;
      c += (eb >= 0xC0u) ? 1u : 0u;
    }
    #pragma unroll
    for (int o = 32; o > 0; o >>= 1) c += __shfl_xor(c, o);
    if ((threadIdx.x & 63) == 0 && c) atomicAdd(&flag[1], c);
  }
}

// ---------- degree count, reading edge dst directly from ei ----------
__global__ void k_deg(const void* __restrict__ ei, int E, int Ep,
                      const uint* __restrict__ flag, int* __restrict__ deg){
  int e = blockIdx.x * blockDim.x + threadIdx.x;
  if (e >= Ep) return;
  int d;
  if (e >= E)        d = e - E;
  else if (flag[0])  d = ((const int*)ei)[(size_t)E + e];
  else               d = (int)((const long long*)ei)[(size_t)E + e];
  atomicAdd(&deg[d], 1);
}

// ---------- CSR scans ----------
__global__ __launch_bounds__(256) void k_scan1(const int* __restrict__ deg,
    int* __restrict__ incl, int* __restrict__ bsum, int N){
  __shared__ int tmp[256];
  int i = blockIdx.x * 256 + threadIdx.x;
  int v = (i < N) ? deg[i] : 0;
  tmp[threadIdx.x] = v; __syncthreads();
  for (int o = 1; o < 256; o <<= 1){
    int t = (threadIdx.x >= o) ? tmp[threadIdx.x - o] : 0;
    __syncthreads();
    tmp[threadIdx.x] += t;
    __syncthreads();
  }
  if (i < N) incl[i] = tmp[threadIdx.x];
  if (threadIdx.x == 255) bsum[blockIdx.x] = tmp[255];
}

__global__ __launch_bounds__(1024) void k_scan2(int* __restrict__ bsum, int nb){
  __shared__ int tmp[1024];
  int t = threadIdx.x;
  int v = (t < nb) ? bsum[t] : 0;
  tmp[t] = v; __syncthreads();
  for (int o = 1; o < 1024; o <<= 1){
    int x = (t >= o) ? tmp[t - o] : 0;
    __syncthreads();
    tmp[t] += x;
    __syncthreads();
  }
  if (t < nb) bsum[t] = tmp[t] - v;     // exclusive
}

__global__ void k_scan2_serial(int* __restrict__ bsum, int nb){
  if (blockIdx.x == 0 && threadIdx.x == 0){
    int run = 0;
    for (int i = 0; i < nb; i++){ int v = bsum[i]; bsum[i] = run; run += v; }
  }
}

__global__ void k_scan3(const int* __restrict__ deg, const int* __restrict__ incl,
                        const int* __restrict__ bsum, int* __restrict__ rowptr,
                        int* __restrict__ cursor, int N, int Ep){
  int i = blockIdx.x * 256 + threadIdx.x;
  if (i < N){
    int r = bsum[blockIdx.x] + incl[i] - deg[i];
    rowptr[i] = r; cursor[i] = r;
  }
  if (i == 0) rowptr[N] = Ep;
}

// ---------- fill CSR, reading ei directly ----------
__global__ void k_fill(const void* __restrict__ ei, int E, int Ep,
                       const uint* __restrict__ flag,
                       int* __restrict__ cursor, int* __restrict__ csr_src, int Ep_){
  int e = blockIdx.x * blockDim.x + threadIdx.x;
  if (e >= Ep) return;
  int s, d;
  if (e >= E){ s = e - E; d = e - E; }
  else if (flag[0]){
    const int* p = (const int*)ei;
    s = p[e]; d = p[(size_t)E + e];
  } else {
    const long long* p = (const long long*)ei;
    s = (int)p[e]; d = (int)p[(size_t)E + e];
  }
  int pos = atomicAdd(&cursor[d], 1);
  csr_src[pos] = s;
}

// ---------- normalize param tensors ----------
__device__ __forceinline__ void cvt8(const void* __restrict__ in, float* __restrict__ out,
                                     int i, bool f32){
  float f[8];
  if (f32){
    const float4* p = (const float4*)((const float*)in + i);
    float4 a = p[0], b = p[1];
    f[0]=a.x; f[1]=a.y; f[2]=a.z; f[3]=a.w; f[4]=b.x; f[5]=b.y; f[6]=b.z; f[7]=b.w;
  } else {
    uint4 v = *(const uint4*)((const ushort*)in + i);
    const uint* vw = (const uint*)&v;
    #pragma unroll
    for (int p = 0; p < 4; p++){
      f[2*p]   = __uint_as_float(vw[p] << 16);
      f[2*p+1] = __uint_as_float(vw[p] & 0xffff0000u);
    }
  }
  *(float4*)(out + i)     = make_float4(f[0], f[1], f[2], f[3]);
  *(float4*)(out + i + 4) = make_float4(f[4], f[5], f[6], f[7]);
}

struct CvtArgs { const void* src[8]; float* dst[8]; int n8[8]; int total8; };
__global__ void k_cvt8(CvtArgs a, const uint* __restrict__ flag){
  int t = blockIdx.x * blockDim.x + threadIdx.x;
  if (t >= a.total8) return;
  int seg = 0, off = t;
  #pragma unroll
  for (int s = 0; s < 8; s++){
    if (off >= a.n8[seg]) { off -= a.n8[seg]; seg++; } else break;
  }
  cvt8(a.src[seg], a.dst[seg], off * 8, is_f32(flag));
}

// ---------- GEMM + fused attention dots ----------
// O[N,M](bf16) = X[N,128] @ W[128,M]; aS/aD[n,h] = h[n,h,:]·attS/attD[h].
// Row r lives in CG(=M/8) consecutive lanes; per-head reduce = 3x shfl_xor over 8 lanes.
// mode 0: X per flag (f32|bf16).  mode 1: X f32.
template<int M, int RT, int H>
__global__ __launch_bounds__(256) void k_gemm(const void* __restrict__ X,
    const float* __restrict__ W, ushort* __restrict__ O,
    const float* __restrict__ attS, const float* __restrict__ attD,
    float* __restrict__ aS, float* __restrict__ aD, int N,
    const uint* __restrict__ flag, int mode){
  constexpr int K = 128;
  __shared__ float Wl[K * M];
  for (int i = threadIdx.x; i < K * M; i += 256) Wl[i] = W[i];
  __syncthreads();
  bool xf32 = (mode == 1) || is_f32(flag);
  constexpr int CG = M / 8;
  int cx = threadIdx.x % CG;
  int ry = threadIdx.x / CG;
  int row0 = blockIdx.x * 64 + ry * RT;
  float acc[RT][8];
  #pragma unroll
  for (int r = 0; r < RT; r++)
    #pragma unroll
    for (int c = 0; c < 8; c++) acc[r][c] = 0.f;

  for (int kb = 0; kb < K; kb += 4){
    float4 xv[RT];
    #pragma unroll
    for (int r = 0; r < RT; r++){
      int row = row0 + r; if (row >= N) row = N - 1;
      if (xf32){
        xv[r] = *(const float4*)((const float*)X + (size_t)row * K + kb);
      } else {
        uint2 u = *(const uint2*)((const ushort*)X + (size_t)row * K + kb);
        xv[r] = make_float4(bflo(u.x), bfhi(u.x), bflo(u.y), bfhi(u.y));
      }
    }
    #pragma unroll
    for (int kk = 0; kk < 4; kk++){
      float wr[8];
      #pragma unroll
      for (int c = 0; c < 8; c++) wr[c] = Wl[(kb + kk) * M + cx * 8 + c];
      #pragma unroll
      for (int r = 0; r < RT; r++){
        float xf = ((const float*)&xv[r])[kk];
        #pragma unroll
        for (int c = 0; c < 8; c++) acc[r][c] = fmaf(xf, wr[c], acc[r][c]);
      }
    }
  }

  // att coefficients for this thread's 8 columns
  int head = (H == 2) ? (cx >> 3) : 0;
  int colh = (H == 2) ? ((cx & 7) * 8) : (cx * 8);
  float sc[8], dc[8];
  #pragma unroll
  for (int c = 0; c < 8; c++){
    sc[c] = attS[head * 64 + colh + c];
    dc[c] = attD[head * 64 + colh + c];
  }

  #pragma unroll
  for (int r = 0; r < RT; r++){
    int row = row0 + r;
    float ps = 0.f, pd = 0.f;
    #pragma unroll
    for (int c = 0; c < 8; c++){
      ps = fmaf(acc[r][c], sc[c], ps);
      pd = fmaf(acc[r][c], dc[c], pd);
    }
    #pragma unroll
    for (int o = 1; o < 8; o <<= 1){
      ps += __shfl_xor(ps, o);
      pd += __shfl_xor(pd, o);
    }
    if (row < N){
      uint4 ov; uint* ow = (uint*)&ov;
      #pragma unroll
      for (int p = 0; p < 4; p++)
        ow[p] = (uint)f2bf(acc[r][2 * p]) | ((uint)f2bf(acc[r][2 * p + 1]) << 16);
      *(uint4*)(O + (size_t)row * M + cx * 8) = ov;
      if ((cx & 7) == 0){
        aS[row * H + head] = ps;
        aD[row * H + head] = pd;
      }
    }
  }
}

// ---------- layer-1 fused agg, H=2 head-merged, bf16 h, LDS-staged alphas, unroll x4 ----------
__global__ __launch_bounds__(256) void k_agg2(const int* __restrict__ rowptr,
    const int* __restrict__ csr_src, const float* __restrict__ aS,
    const float* __restrict__ aD, const ushort* __restrict__ Hb,
    const float2* __restrict__ bias2, float2* __restrict__ out2, int N){
  __shared__ int   Ls[4][64];
  __shared__ float L0[4][64];
  __shared__ float L1[4][64];
  const uint* Hrow = (const uint*)Hb;
  int wv   = threadIdx.x >> 6;
  int lane = threadIdx.x & 63;
  int wid  = (blockIdx.x * 256 + threadIdx.x) >> 6;
  if (wid >= N) return;
  int d = wid;
  int r0 = rowptr[d], r1 = rowptr[d + 1];
  int cnt = r1 - r0;
  float aD0 = aD[d * 2], aD1 = aD[d * 2 + 1];
  float2 acc = make_float2(0.f, 0.f);

  if (cnt <= 64){
    int   sj = 0;
    float v0 = -1e30f, v1 = -1e30f;
    if (lane < cnt){
      sj = csr_src[r0 + lane];
      v0 = leaky(aS[sj * 2]     + aD0);
      v1 = leaky(aS[sj * 2 + 1] + aD1);
    }
    float M0 = v0, M1 = v1;
    #pragma unroll
    for (int o = 1; o < 64; o <<= 1){
      M0 = fmaxf(M0, __shfl_xor(M0, o));
      M1 = fmaxf(M1, __shfl_xor(M1, o));
    }
    float e0 = (lane < cnt) ? __expf(v0 - M0) : 0.f;
    float e1 = (lane < cnt) ? __expf(v1 - M1) : 0.f;
    float S0 = e0, S1 = e1;
    #pragma unroll
    for (int o = 1; o < 64; o <<= 1){
      S0 += __shfl_xor(S0, o);
      S1 += __shfl_xor(S1, o);
    }
    Ls[wv][lane] = sj;                       // junk lanes: sj=0, alpha=0 (safe)
    L0[wv][lane] = e0 / (S0 + 1e-16f);
    L1[wv][lane] = e1 / (S1 + 1e-16f);
    for (int i = 0; i < cnt; i += 4){
      int4   s4 = *(const int4*)  &Ls[wv][i];
      float4 a4 = *(const float4*)&L0[wv][i];
      float4 b4 = *(const float4*)&L1[wv][i];
      uint h0 = Hrow[(size_t)s4.x * 64 + lane];
      uint h1 = Hrow[(size_t)s4.y * 64 + lane];
      uint h2 = Hrow[(size_t)s4.z * 64 + lane];
      uint h3 = Hrow[(size_t)s4.w * 64 + lane];
      float w0 = (lane < 32) ? a4.x : b4.x;
      float w1 = (lane < 32) ? a4.y : b4.y;
      float w2 = (lane < 32) ? a4.z : b4.z;
      float w3 = (lane < 32) ? a4.w : b4.w;
      acc.x = fmaf(w0, bflo(h0), acc.x); acc.y = fmaf(w0, bfhi(h0), acc.y);
      acc.x = fmaf(w1, bflo(h1), acc.x); acc.y = fmaf(w1, bfhi(h1), acc.y);
      acc.x = fmaf(w2, bflo(h2), acc.x); acc.y = fmaf(w2, bfhi(h2), acc.y);
      acc.x = fmaf(w3, bflo(h3), acc.x); acc.y = fmaf(w3, bfhi(h3), acc.y);
    }
  } else {
    float m0 = -1e30f, s0 = 0.f, m1 = -1e30f, s1 = 0.f;
    for (int j = r0 + lane; j < r1; j += 64){
      int sj = csr_src[j];
      float v0 = leaky(aS[sj * 2]     + aD0);
      float v1 = leaky(aS[sj * 2 + 1] + aD1);
      if (v0 > m0){ s0 = s0 * __expf(m0 - v0) + 1.f; m0 = v0; } else s0 += __expf(v0 - m0);
      if (v1 > m1){ s1 = s1 * __expf(m1 - v1) + 1.f; m1 = v1; } else s1 += __expf(v1 - m1);
    }
    #pragma unroll
    for (int o = 1; o < 64; o <<= 1){
      float mo = __shfl_xor(m0, o), so = __shfl_xor(s0, o);
      float M = fmaxf(m0, mo);
      s0 = s0 * __expf(m0 - M) + so * __expf(mo - M); m0 = M;
      mo = __shfl_xor(m1, o); so = __shfl_xor(s1, o);
      M = fmaxf(m1, mo);
      s1 = s1 * __expf(m1 - M) + so * __expf(mo - M); m1 = M;
    }
    float inv0 = 1.f / (s0 + 1e-16f), inv1 = 1.f / (s1 + 1e-16f);
    for (int j = r0; j < r1; j++){
      int sj = csr_src[j];
      float al0 = __expf(leaky(aS[sj * 2]     + aD0) - m0) * inv0;
      float al1 = __expf(leaky(aS[sj * 2 + 1] + aD1) - m1) * inv1;
      float ah = (lane < 32) ? al0 : al1;
      uint hv = Hrow[(size_t)sj * 64 + lane];
      acc.x = fmaf(ah, bflo(hv), acc.x);
      acc.y = fmaf(ah, bfhi(hv), acc.y);
    }
  }

  float2 b = bias2[lane];
  float o0 = acc.x + b.x, o1 = acc.y + b.y;
  o0 = o0 > 0.f ? o0 : expm1f(o0);
  o1 = o1 > 0.f ? o1 : expm1f(o1);
  out2[(size_t)d * 64 + lane] = make_float2(o0, o1);
}

// ---------- layer-2 fused agg, H=1, bf16 h, LDS-staged alphas, unroll x4 ----------
__global__ __launch_bounds__(256) void k_agg1(const int* __restrict__ rowptr,
    const int* __restrict__ csr_src, const float* __restrict__ aS,
    const float* __restrict__ aD, const ushort* __restrict__ Hb,
    const float* __restrict__ bias, void* __restrict__ outp, int N,
    const uint* __restrict__ flag){
  __shared__ int   Ls[4][64];
  __shared__ float La[4][64];
  int wv   = threadIdx.x >> 6;
  int lane = threadIdx.x & 63;
  int wid  = (blockIdx.x * 256 + threadIdx.x) >> 6;
  if (wid >= N) return;
  int d = wid;
  int r0 = rowptr[d], r1 = rowptr[d + 1];
  int cnt = r1 - r0;
  float aDd = aD[d];
  float acc = 0.f;

  if (cnt <= 64){
    int   sj = 0;
    float v = -1e30f;
    if (lane < cnt){
      sj = csr_src[r0 + lane];
      v = leaky(aS[sj] + aDd);
    }
    float M = v;
    #pragma unroll
    for (int o = 1; o < 64; o <<= 1) M = fmaxf(M, __shfl_xor(M, o));
    float e = (lane < cnt) ? __expf(v - M) : 0.f;
    float S = e;
    #pragma unroll
    for (int o = 1; o < 64; o <<= 1) S += __shfl_xor(S, o);
    Ls[wv][lane] = sj;
    La[wv][lane] = e / (S + 1e-16f);
    for (int i = 0; i < cnt; i += 4){
      int4   s4 = *(const int4*)  &Ls[wv][i];
      float4 a4 = *(const float4*)&La[wv][i];
      float g0 = bf2f(Hb[(size_t)s4.x * 64 + lane]);
      float g1 = bf2f(Hb[(size_t)s4.y * 64 + lane]);
      float g2 = bf2f(Hb[(size_t)s4.z * 64 + lane]);
      float g3 = bf2f(Hb[(size_t)s4.w * 64 + lane]);
      acc = fmaf(a4.x, g0, acc);
      acc = fmaf(a4.y, g1, acc);
      acc = fmaf(a4.z, g2, acc);
      acc = fmaf(a4.w, g3, acc);
    }
  } else {
    float m = -1e30f, s = 0.f;
    for (int j = r0 + lane; j < r1; j += 64){
      int sj = csr_src[j];
      float v = leaky(aS[sj] + aDd);
      if (v > m){ s = s * __expf(m - v) + 1.f; m = v; } else s += __expf(v - m);
    }
    #pragma unroll
    for (int o = 1; o < 64; o <<= 1){
      float mo = __shfl_xor(m, o), so = __shfl_xor(s, o);
      float M = fmaxf(m, mo);
      s = s * __expf(m - M) + so * __expf(mo - M); m = M;
    }
    float inv = 1.f / (s + 1e-16f);
    for (int j = r0; j < r1; j++){
      int sj = csr_src[j];
      float al = __expf(leaky(aS[sj] + aDd) - m) * inv;
      acc = fmaf(al, bf2f(Hb[(size_t)sj * 64 + lane]), acc);
    }
  }

  float o = acc + bias[lane];
  if (is_f32(flag)) ((float*)outp)[(size_t)d * 64 + lane] = o;
  else              ((ushort*)outp)[(size_t)d * 64 + lane] = f2bf(o);
}

extern "C" void kernel_launch(void* const* d_in, const int* in_sizes, int n_in,
                              void* d_out, int out_size, void* d_ws, size_t ws_size,
                              hipStream_t stream){
  const void* x   = d_in[0];
  const void* ei  = d_in[1];
  const void* W1  = d_in[2];
  const void* aS1w= d_in[3];
  const void* aD1w= d_in[4];
  const void* b1w = d_in[5];
  const void* W2  = d_in[6];
  const void* aS2w= d_in[7];
  const void* aD2w= d_in[8];
  const void* b2w = d_in[9];

  const int N  = in_sizes[0] / 128;
  const int E  = in_sizes[1] / 2;
  const int Ep = E + N;
  const int nb = (N + 255) / 256;

  char* w = (char*)d_ws;
  size_t off = 0;
  auto alloc = [&](size_t bytes)->char*{
    char* p = w + off; off = (off + bytes + 255) & ~(size_t)255; return p;
  };
  uint*  flag   = (uint*) alloc(256);
  int*   csr    = (int*)  alloc((size_t)Ep * 4);
  int*   deg    = (int*)  alloc((size_t)N * 4);
  int*   incl   = (int*)  alloc((size_t)N * 4);
  int*   rowptr = (int*)  alloc((size_t)(N + 1) * 4);
  int*   cursor = (int*)  alloc((size_t)N * 4);
  int*   bsum   = (int*)  alloc((size_t)nb * 4);
  float* Wf1    = (float*)alloc((size_t)128 * 128 * 4);
  float* aSf1   = (float*)alloc(128 * 4);
  float* aDf1   = (float*)alloc(128 * 4);
  float* bf1    = (float*)alloc(128 * 4);
  float* Wf2    = (float*)alloc((size_t)128 * 64 * 4);
  float* aSf2   = (float*)alloc(64 * 4);
  float* aDf2   = (float*)alloc(64 * 4);
  float* bf2    = (float*)alloc(64 * 4);
  float* aS1    = (float*)alloc((size_t)N * 2 * 4);
  float* aD1    = (float*)alloc((size_t)N * 2 * 4);
  float* aS2    = (float*)alloc((size_t)N * 4);
  float* aD2    = (float*)alloc((size_t)N * 4);
  float* A      = (float*)alloc((size_t)N * 128 * 4);   // agg2 out (f32) = gemm2 in
  ushort* B     = (ushort*)alloc((size_t)N * 128 * 2);  // h (bf16), both layers

  hipMemsetAsync(flag, 0, 8, stream);
  hipMemsetAsync(deg, 0, (size_t)N * 4, stream);

  int enw = 2 * E; if (enw > 131072) enw = 131072;
  int xnw = N * 128; if (xnw > 65536) xnw = 65536;
  k_detect<<<32, 256, 0, stream>>>((const uint*)ei, enw, (const uint*)x, xnw, flag);

  int gbE = (Ep + 255) / 256;
  // ---- CSR build ----
  k_deg  <<<gbE, 256, 0, stream>>>(ei, E, Ep, flag, deg);
  k_scan1<<<nb, 256, 0, stream>>>(deg, incl, bsum, N);
  if (nb <= 1024) k_scan2<<<1, 1024, 0, stream>>>(bsum, nb);
  else            k_scan2_serial<<<1, 64, 0, stream>>>(bsum, nb);
  k_scan3<<<nb, 256, 0, stream>>>(deg, incl, bsum, rowptr, cursor, N, Ep);
  k_fill <<<gbE, 256, 0, stream>>>(ei, E, Ep, flag, cursor, csr, Ep);

  // ---- normalize param tensors to f32 (one launch) ----
  {
    CvtArgs a;
    a.src[0]=W1;  a.dst[0]=Wf1;  a.n8[0]=128*128/8;
    a.src[1]=W2;  a.dst[1]=Wf2;  a.n8[1]=128*64/8;
    a.src[2]=aS1w;a.dst[2]=aSf1; a.n8[2]=16;
    a.src[3]=aD1w;a.dst[3]=aDf1; a.n8[3]=16;
    a.src[4]=b1w; a.dst[4]=bf1;  a.n8[4]=16;
    a.src[5]=aS2w;a.dst[5]=aSf2; a.n8[5]=8;
    a.src[6]=aD2w;a.dst[6]=aDf2; a.n8[6]=8;
    a.src[7]=b2w; a.dst[7]=bf2;  a.n8[7]=8;
    a.total8 = 128*128/8 + 128*64/8 + 16*3 + 8*3;
    k_cvt8<<<(a.total8 + 255) / 256, 256, 0, stream>>>(a, flag);
  }

  int gemmb = (N + 63) / 64;
  // -------- layer 1 (H=2): gemm+att -> head-merged agg(+bias+ELU) --------
  k_gemm<128, 4, 2><<<gemmb, 256, 0, stream>>>(x, Wf1, B, aSf1, aDf1, aS1, aD1, N, flag, 0);
  {
    int blocks = (N * 64 + 255) / 256;
    k_agg2<<<blocks, 256, 0, stream>>>(rowptr, csr, aS1, aD1, B,
                                       (const float2*)bf1, (float2*)A, N);
  }
  // -------- layer 2 (H=1): gemm+att -> agg(+bias) --------
  k_gemm<64, 2, 1><<<gemmb, 256, 0, stream>>>(A, Wf2, B, aSf2, aDf2, aS2, aD2, N, flag, 1);
  {
    int blocks = (N * 64 + 255) / 256;
    k_agg1<<<blocks, 256, 0, stream>>>(rowptr, csr, aS2, aD2, B, bf2, d_out, N, flag);
  }
}